// Round 5
// baseline (52.080 us; speedup 1.0000x reference)
//
#include <hip/hip_runtime.h>

#define NPIX   3136        // 56*56
#define MROWS  12544       // 4*3136
#define QKV_STRIDE 1605632 // MROWS*128 halves per q/k/v buffer
#define SCALE  0.17677669529663687f  // 32^-0.5

typedef __attribute__((ext_vector_type(8))) _Float16 half8;
typedef __attribute__((ext_vector_type(2))) _Float16 v2h;
typedef __attribute__((ext_vector_type(4))) float    f32x4;

#if defined(__has_builtin)
#if __has_builtin(__builtin_amdgcn_fdot2)
#define HAS_FDOT2 1
#endif
#endif

// sum across each aligned quad of 4 lanes via DPP quad_perm
__device__ __forceinline__ float quad_reduce_sum(float x) {
    x += __int_as_float(__builtin_amdgcn_mov_dpp(__float_as_int(x), 0xB1, 0xF, 0xF, true));
    x += __int_as_float(__builtin_amdgcn_mov_dpp(__float_as_int(x), 0x4E, 0xF, 0xF, true));
    return x;
}

// 8-wide fp16 dot with fp32 accumulate (v_dot2_f32_f16 x4)
__device__ __forceinline__ float dot8h(half8 a, half8 b, float acc) {
#ifdef HAS_FDOT2
    union { half8 v; v2h p[4]; } ua, ub;
    ua.v = a; ub.v = b;
    acc = __builtin_amdgcn_fdot2(ua.p[0], ub.p[0], acc, false);
    acc = __builtin_amdgcn_fdot2(ua.p[1], ub.p[1], acc, false);
    acc = __builtin_amdgcn_fdot2(ua.p[2], ub.p[2], acc, false);
    acc = __builtin_amdgcn_fdot2(ua.p[3], ub.p[3], acc, false);
#else
#pragma unroll
    for (int i = 0; i < 8; ++i) acc += (float)a[i] * (float)b[i];
#endif
    return acc;
}

__device__ __forceinline__ half8 cvt8(float4 a, float4 b) {
    half8 r;
    r[0] = (_Float16)a.x; r[1] = (_Float16)a.y;
    r[2] = (_Float16)a.z; r[3] = (_Float16)a.w;
    r[4] = (_Float16)b.x; r[5] = (_Float16)b.y;
    r[6] = (_Float16)b.z; r[7] = (_Float16)b.w;
    return r;
}

// ---------------------------------------------------------------------------
// LDS-free direct-fragment MFMA GEMM: out = A[M][128] * W[N][128]^T + bias.
// The 16x16x32 fragment layout (m=l&15, k=(l>>4)*8+i) is 8 contiguous
// k-elements per lane -> loadable straight from row-major global memory.
// No __shared__, no barriers: every wave is an independent 16FM x 16FN tile,
// latency hidden purely by wave-level parallelism. W re-reads are L2-hot
// (W <= 192 KB total).
// AHALF: A is fp16 (att) -> one b128 load per fragment; else fp32 + cvt.
// EPI=0: scatter fp16 q/k/v [which][b*4+head][pix][32]
// EPI=1: write fp32 out[row][128]
// D map: col=l&15, row=(l>>4)*4+reg  [m89-verified, validated rounds 3-4].
// ---------------------------------------------------------------------------
template<int AHALF, int EPI, int FM, int FN, int MTILES>
__global__ __launch_bounds__(256)
void gemm_direct(const void* __restrict__ Av, const float* __restrict__ W,
                 const float* __restrict__ bias, void* __restrict__ outv)
{
    const int t    = threadIdx.x;
    const int gwid = blockIdx.x * 4 + (t >> 6);   // global wave id
    const int row0 = (gwid % MTILES) * (FM * 16);
    const int col0 = (gwid / MTILES) * (FN * 16);
    const int l    = t & 63;
    const int lm   = l & 15;           // fragment row (m or n)
    const int lk   = (l >> 4) << 3;    // fragment k base within 32-step

    f32x4 acc[FM][FN];
#pragma unroll
    for (int mf = 0; mf < FM; ++mf)
#pragma unroll
        for (int nf = 0; nf < FN; ++nf) acc[mf][nf] = (f32x4){0.f, 0.f, 0.f, 0.f};

#pragma unroll
    for (int ks = 0; ks < 4; ++ks) {
        const int kb = ks * 32 + lk;
        half8 a[FM], b[FN];
#pragma unroll
        for (int mf = 0; mf < FM; ++mf) {
            const size_t off = (size_t)(row0 + mf * 16 + lm) * 128 + kb;
            if constexpr (AHALF) {
                a[mf] = *reinterpret_cast<const half8*>((const _Float16*)Av + off);
            } else {
                const float* A = (const float*)Av;
                float4 x0 = *reinterpret_cast<const float4*>(A + off);
                float4 x1 = *reinterpret_cast<const float4*>(A + off + 4);
                a[mf] = cvt8(x0, x1);
            }
        }
#pragma unroll
        for (int nf = 0; nf < FN; ++nf) {
            const size_t off = (size_t)(col0 + nf * 16 + lm) * 128 + kb;
            float4 w0 = *reinterpret_cast<const float4*>(W + off);
            float4 w1 = *reinterpret_cast<const float4*>(W + off + 4);
            b[nf] = cvt8(w0, w1);
        }
#pragma unroll
        for (int mf = 0; mf < FM; ++mf)
#pragma unroll
            for (int nf = 0; nf < FN; ++nf)
                acc[mf][nf] = __builtin_amdgcn_mfma_f32_16x16x32_f16(
                    a[mf], b[nf], acc[mf][nf], 0, 0, 0);
    }

    // ---- epilogue ----
#pragma unroll
    for (int mf = 0; mf < FM; ++mf) {
#pragma unroll
        for (int nf = 0; nf < FN; ++nf) {
#pragma unroll
            for (int r = 0; r < 4; ++r) {
                int row = row0 + mf * 16 + ((l >> 4) << 2) + r;
                int col = col0 + nf * 16 + lm;
                float val = acc[mf][nf][r] + bias[col];
                if (EPI == 1) {
                    ((float*)outv)[(size_t)row * 128 + col] = val;
                } else {
                    int b_  = row / NPIX;
                    int pix = row - b_ * NPIX;
                    int which = col >> 7;          // 0=q 1=k 2=v
                    int head  = (col & 127) >> 5;
                    int d     = col & 31;
                    ((_Float16*)outv)[(size_t)which * QKV_STRIDE +
                        ((size_t)(b_ * 4 + head) * NPIX + pix) * 32 + d] = (_Float16)val;
                }
            }
        }
    }
}

// ---------------------------------------------------------------------------
// Neighborhood attention, fp16 data / fp32 accum.
// 256-thread block per (8x8 pixel tile, head, batch); 4 lanes per pixel,
// each owning an 8-half d-slice (one ds_read_b128 per neighbor); quad logit
// reduce via DPP. K then V staged in the same fp16 LDS buffer.
// ROW STRIDE = 40 halves (80 B = 5 granules; 5 coprime 8): consecutive nb
// rows cycle all 8 bank-quads -> 2 lanes/quad per sub-class = conflict-free.
// (Round-4's stride 32 put all 16 quads of a wave on ONE bank-quad: 8-way
// conflict on every kvs read.)
// OOB neighbors stay zero -> logit = bias only, kept in softmax (matches
// reference zero-padding).
// ---------------------------------------------------------------------------
#define KVSTR 40
__global__ __launch_bounds__(256, 3)
void natten_k(const _Float16* __restrict__ qb, const _Float16* __restrict__ kb,
              const _Float16* __restrict__ vb, const float* __restrict__ rpb,
              _Float16* __restrict__ att)
{
    const int tile = blockIdx.x;          // 0..48
    const int h    = blockIdx.y;          // 0..3
    const int b    = blockIdx.z;          // 0..3
    const int ti = (tile / 7) * 8;
    const int tj = (tile % 7) * 8;
    const int t   = threadIdx.x;
    const int sub = t & 3;                // d-slice owner within the quad
    const int pl  = t >> 2;               // 0..63 local pixel
    const int pi  = pl >> 3;
    const int pj  = pl & 7;

    __shared__ _Float16 kvs[196 * KVSTR]; // 15.7 KB, K then V

    const size_t hb = (size_t)(b * 4 + h) * NPIX * 32;
    const _Float16* kbase = kb + hb;
    const _Float16* vbase = vb + hb;

    // ---- stage K: 784 16B-granules over 256 threads ----
    for (int e = t; e < 196 * 4; e += 256) {
        int p = e >> 2;
        int g = e & 3;
        int wi = p / 14;
        int wj = p - wi * 14;
        int gi = ti - 3 + wi;
        int gj = tj - 3 + wj;
        half8 kv = (half8){0,0,0,0,0,0,0,0};
        if (((unsigned)gi < 56u) && ((unsigned)gj < 56u))
            kv = *reinterpret_cast<const half8*>(kbase + (gi * 56 + gj) * 32 + g * 8);
        *reinterpret_cast<half8*>(&kvs[p * KVSTR + g * 8]) = kv;
    }

    // ---- load this lane's q d-slice while K staging is in flight ----
    const int pix = (ti + pi) * 56 + (tj + pj);
    half8 qv = *reinterpret_cast<const half8*>(qb + hb + (size_t)pix * 32 + sub * 8);

    __syncthreads();

    // ---- QK^T + bias ----
    const float* bias = rpb + h * 169;
    float logits[49];
    float m = -1e30f;
#pragma unroll
    for (int ki = 0; ki < 7; ++ki) {
#pragma unroll
        for (int kj = 0; kj < 7; ++kj) {
            int nb = (pi + ki) * 14 + (pj + kj);
            half8 kk = *reinterpret_cast<const half8*>(&kvs[nb * KVSTR + sub * 8]);
            float s = dot8h(qv, kk, 0.f);
            s = quad_reduce_sum(s);       // full 32-d dot in all 4 lanes
            float lg = s * SCALE + bias[(ki + 3) * 13 + (kj + 3)];
            logits[ki * 7 + kj] = lg;
            m = fmaxf(m, lg);
        }
    }

    // ---- softmax (redundant per quad lane; cheap) ----
    float sum = 0.f;
#pragma unroll
    for (int n = 0; n < 49; ++n) {
        float e = __expf(logits[n] - m);
        logits[n] = e;
        sum += e;
    }
    float inv = 1.f / sum;

    // ---- stage V into the same LDS ----
    __syncthreads();   // everyone done reading K
    for (int e = t; e < 196 * 4; e += 256) {
        int p = e >> 2;
        int g = e & 3;
        int wi = p / 14;
        int wj = p - wi * 14;
        int gi = ti - 3 + wi;
        int gj = tj - 3 + wj;
        half8 vv = (half8){0,0,0,0,0,0,0,0};
        if (((unsigned)gi < 56u) && ((unsigned)gj < 56u))
            vv = *reinterpret_cast<const half8*>(vbase + (gi * 56 + gj) * 32 + g * 8);
        *reinterpret_cast<half8*>(&kvs[p * KVSTR + g * 8]) = vv;
    }
    __syncthreads();

    // ---- P·V (fp32 accum) ----
    float o[8] = {0.f, 0.f, 0.f, 0.f, 0.f, 0.f, 0.f, 0.f};
#pragma unroll
    for (int ki = 0; ki < 7; ++ki) {
#pragma unroll
        for (int kj = 0; kj < 7; ++kj) {
            int nb = (pi + ki) * 14 + (pj + kj);
            half8 vv = *reinterpret_cast<const half8*>(&kvs[nb * KVSTR + sub * 8]);
            float wgt = logits[ki * 7 + kj];
#pragma unroll
            for (int i = 0; i < 8; ++i)
                o[i] += wgt * (float)vv[i];
        }
    }

    // ---- write fp16 att, layout [b][pix][h*32+d] for the proj GEMM ----
    _Float16* dst = att + ((size_t)b * NPIX + pix) * 128 + h * 32 + sub * 8;
    half8 r;
#pragma unroll
    for (int i = 0; i < 8; ++i) r[i] = (_Float16)(o[i] * inv);
    *reinterpret_cast<half8*>(dst) = r;
}

// ---------------------------------------------------------------------------
extern "C" void kernel_launch(void* const* d_in, const int* in_sizes, int n_in,
                              void* d_out, int out_size, void* d_ws, size_t ws_size,
                              hipStream_t stream)
{
    const float* x      = (const float*)d_in[0];
    const float* qkv_w  = (const float*)d_in[1];
    const float* qkv_b  = (const float*)d_in[2];
    const float* rpb    = (const float*)d_in[3];
    const float* proj_w = (const float*)d_in[4];
    const float* proj_b = (const float*)d_in[5];
    float* out = (float*)d_out;

    // ws layout (fp16): q | k | v | att  (3.2 MB each, 12.8 MB total)
    _Float16* qbuf = (_Float16*)d_ws;
    _Float16* kbuf = qbuf + (size_t)QKV_STRIDE;
    _Float16* vbuf = kbuf + (size_t)QKV_STRIDE;
    _Float16* att  = vbuf + (size_t)QKV_STRIDE;

    // 1) QKV projection: [12544,128] @ [384,128]^T -> fp16 q/k/v scatter
    //    wave tile 32x64 (FM=2,FN=4), 392 m-tiles x 6 n-tiles = 2352 waves
    gemm_direct<0, 0, 2, 4, 392><<<dim3(588), dim3(256), 0, stream>>>(
        x, qkv_w, qkv_b, qbuf);

    // 2) neighborhood attention: 784 blocks x 4 waves, fp16 in/out
    natten_k<<<dim3(49, 4, 4), dim3(256), 0, stream>>>(qbuf, kbuf, vbuf, rpb, att);

    // 3) output projection: [12544,128] @ [128,128]^T, fp16 A -> fp32 out
    //    wave tile 16x64 (FM=1,FN=4), 784 m-tiles x 2 n-tiles = 1568 waves
    gemm_direct<1, 1, 1, 4, 784><<<dim3(392), dim3(256), 0, stream>>>(
        att, proj_w, proj_b, out);
}

// Round 6
// 42.086 us; speedup vs baseline: 1.2375x; 1.2375x over previous
//
#include <hip/hip_runtime.h>

#define NPIX   3136        // 56*56
#define MROWS  12544       // 4*3136
#define QKV_STRIDE 1605632 // MROWS*128 halves per q/k/v buffer
#define SCALE  0.17677669529663687f  // 32^-0.5

typedef __attribute__((ext_vector_type(8))) _Float16 half8;
typedef __attribute__((ext_vector_type(2))) _Float16 v2h;
typedef __attribute__((ext_vector_type(4))) float    f32x4;

#if defined(__has_builtin)
#if __has_builtin(__builtin_amdgcn_fdot2)
#define HAS_FDOT2 1
#endif
#endif

// sum across each aligned quad of 4 lanes via DPP quad_perm
__device__ __forceinline__ float quad_reduce_sum(float x) {
    x += __int_as_float(__builtin_amdgcn_mov_dpp(__float_as_int(x), 0xB1, 0xF, 0xF, true));
    x += __int_as_float(__builtin_amdgcn_mov_dpp(__float_as_int(x), 0x4E, 0xF, 0xF, true));
    return x;
}

// 8-wide fp16 dot with fp32 accumulate (v_dot2_f32_f16 x4)
__device__ __forceinline__ float dot8h(half8 a, half8 b, float acc) {
#ifdef HAS_FDOT2
    union { half8 v; v2h p[4]; } ua, ub;
    ua.v = a; ub.v = b;
    acc = __builtin_amdgcn_fdot2(ua.p[0], ub.p[0], acc, false);
    acc = __builtin_amdgcn_fdot2(ua.p[1], ub.p[1], acc, false);
    acc = __builtin_amdgcn_fdot2(ua.p[2], ub.p[2], acc, false);
    acc = __builtin_amdgcn_fdot2(ua.p[3], ub.p[3], acc, false);
#else
#pragma unroll
    for (int i = 0; i < 8; ++i) acc += (float)a[i] * (float)b[i];
#endif
    return acc;
}

// ---------------------------------------------------------------------------
// MFMA GEMM (round-4 known-good version): out = A[M][128] * W[N][128]^T +
// bias, fp16 MFMA / fp32 accum. Full K=128 staged once in LDS (coalesced
// loads, cvt once, 12-cyc ds_read_b128 fragments). LDS fp16 [rows][128] with
// XOR swizzle k ^ ((r&7)<<3) (half units).
// Round-5 lesson: the LDS-free direct-fragment variant regressed 17us —
// scattered per-wave global fragment loads at ~2.3 waves/SIMD can't hide L2
// latency and re-fetch W per wave. Keep the staged form.
// Fragment maps (16x16x32): A: m=l&15, k=(l>>4)*8+i; B mirrored;
// D: col=l&15, row=(l>>4)*4+reg  [m89-verified, validated rounds 3-4].
// EPI=0: A fp32, scatter fp16 q/k/v [which][b*4+head][pix][32]
// EPI=1: A fp16 (att), write fp32 out[row][128]
// ---------------------------------------------------------------------------
template<int EPI, int BM, int BN, int WM, int WN>
__global__ __launch_bounds__(256)
void gemm_mfma(const void* __restrict__ Av, const float* __restrict__ W,
               const float* __restrict__ bias, void* __restrict__ outv)
{
    constexpr int WTM = BM / WM;
    constexpr int WTN = BN / WN;
    constexpr int FM  = WTM / 16;
    constexpr int FN  = WTN / 16;
    const int row0 = blockIdx.x * BM;
    const int col0 = blockIdx.y * BN;
    const int t  = threadIdx.x;
    const int w  = t >> 6;
    const int l  = t & 63;
    const int wm = w / WN;
    const int wn = w % WN;

    __shared__ _Float16 Ah[BM * 128];
    __shared__ _Float16 Wh[BN * 128];

    // ---- stage A ----
    if (EPI == 0) {
        const float* A = (const float*)Av;
        constexpr int AIT = BM * 32 / 256;          // float4s per thread
#pragma unroll
        for (int it = 0; it < AIT; ++it) {
            int idx = t + it * 256;
            int r = idx >> 5, k0 = (idx & 31) << 2; // k0 in halves (4-half granule)
            float4 v = *reinterpret_cast<const float4*>(A + (size_t)(row0 + r) * 128 + k0);
            union { _Float16 h[4]; uint2 u; } cv;
            cv.h[0] = (_Float16)v.x; cv.h[1] = (_Float16)v.y;
            cv.h[2] = (_Float16)v.z; cv.h[3] = (_Float16)v.w;
            *reinterpret_cast<uint2*>(&Ah[r * 128 + (k0 ^ ((r & 7) << 3))]) = cv.u;
        }
    } else {
        const _Float16* A = (const _Float16*)Av;
        constexpr int AIT = BM * 16 / 256;          // half8s per thread
#pragma unroll
        for (int it = 0; it < AIT; ++it) {
            int idx = t + it * 256;
            int r = idx >> 4, k0 = (idx & 15) << 3; // k0 in halves (8-half granule)
            half8 v = *reinterpret_cast<const half8*>(A + (size_t)(row0 + r) * 128 + k0);
            *reinterpret_cast<half8*>(&Ah[r * 128 + (k0 ^ ((r & 7) << 3))]) = v;
        }
    }
    // ---- stage W (fp32 global -> fp16 LDS) ----
    {
        constexpr int WIT = BN * 32 / 256;
#pragma unroll
        for (int it = 0; it < WIT; ++it) {
            int idx = t + it * 256;
            int r = idx >> 5, k0 = (idx & 31) << 2;
            float4 v = *reinterpret_cast<const float4*>(W + (size_t)(col0 + r) * 128 + k0);
            union { _Float16 h[4]; uint2 u; } cv;
            cv.h[0] = (_Float16)v.x; cv.h[1] = (_Float16)v.y;
            cv.h[2] = (_Float16)v.z; cv.h[3] = (_Float16)v.w;
            *reinterpret_cast<uint2*>(&Wh[r * 128 + (k0 ^ ((r & 7) << 3))]) = cv.u;
        }
    }
    __syncthreads();

    f32x4 acc[FM][FN];
#pragma unroll
    for (int mf = 0; mf < FM; ++mf)
#pragma unroll
        for (int nf = 0; nf < FN; ++nf) acc[mf][nf] = (f32x4){0.f, 0.f, 0.f, 0.f};

#pragma unroll
    for (int ks = 0; ks < 4; ++ks) {
        const int kb = ks * 32 + ((l >> 4) << 3);
        half8 a[FM], b[FN];
#pragma unroll
        for (int mf = 0; mf < FM; ++mf) {
            int m = wm * WTM + mf * 16 + (l & 15);
            a[mf] = *reinterpret_cast<const half8*>(&Ah[m * 128 + (kb ^ ((m & 7) << 3))]);
        }
#pragma unroll
        for (int nf = 0; nf < FN; ++nf) {
            int n = wn * WTN + nf * 16 + (l & 15);
            b[nf] = *reinterpret_cast<const half8*>(&Wh[n * 128 + (kb ^ ((n & 7) << 3))]);
        }
#pragma unroll
        for (int mf = 0; mf < FM; ++mf)
#pragma unroll
            for (int nf = 0; nf < FN; ++nf)
                acc[mf][nf] = __builtin_amdgcn_mfma_f32_16x16x32_f16(
                    a[mf], b[nf], acc[mf][nf], 0, 0, 0);
    }

    // ---- epilogue ----
#pragma unroll
    for (int mf = 0; mf < FM; ++mf) {
#pragma unroll
        for (int nf = 0; nf < FN; ++nf) {
#pragma unroll
            for (int r = 0; r < 4; ++r) {
                int row = row0 + wm * WTM + mf * 16 + ((l >> 4) << 2) + r;
                int col = col0 + wn * WTN + nf * 16 + (l & 15);
                float val = acc[mf][nf][r] + bias[col];
                if (EPI == 1) {
                    ((float*)outv)[(size_t)row * 128 + col] = val;
                } else {
                    int b_  = row / NPIX;
                    int pix = row - b_ * NPIX;
                    int which = col >> 7;          // 0=q 1=k 2=v
                    int head  = (col & 127) >> 5;
                    int d     = col & 31;
                    ((_Float16*)outv)[(size_t)which * QKV_STRIDE +
                        ((size_t)(b_ * 4 + head) * NPIX + pix) * 32 + d] = (_Float16)val;
                }
            }
        }
    }
}

// ---------------------------------------------------------------------------
// Neighborhood attention, fp16 data / fp32 accum.
// 256-thread block per (8x8 pixel tile, head, batch); 4 lanes per pixel,
// each owning an 8-half d-slice; quad logit reduce via DPP.
// LDS-pipe model (round-5 post-mortem): QK+PV both from LDS = 12 waves x 98
// b128 x 12cyc = 14.1k LDS-cyc per CU batch vs 5.6k VALU -> LDS-bound 2.5x.
// Fix: K stays in LDS (QK^T); V is read DIRECTLY FROM GLOBAL in PV — for
// fixed (ki,kj) the wave's V rows are contiguous across pj (coalesced
// 2x512B), and the 12.5KB per-block V-halo is L1-resident during PV. Halves
// LDS traffic, deletes V staging + 2 of 3 barriers. OOB neighbors: skipped
// in PV (V=0 -> term 0); their exp stays in the softmax denominator
// (matches reference zero-padding semantics).
// ---------------------------------------------------------------------------
#define KVSTR 40
__global__ __launch_bounds__(256, 3)
void natten_k(const _Float16* __restrict__ qb, const _Float16* __restrict__ kb,
              const _Float16* __restrict__ vb, const float* __restrict__ rpb,
              _Float16* __restrict__ att)
{
    const int tile = blockIdx.x;          // 0..48
    const int h    = blockIdx.y;          // 0..3
    const int b    = blockIdx.z;          // 0..3
    const int ti = (tile / 7) * 8;
    const int tj = (tile % 7) * 8;
    const int t   = threadIdx.x;
    const int sub = t & 3;                // d-slice owner within the quad
    const int pl  = t >> 2;               // 0..63 local pixel
    const int pi  = pl >> 3;
    const int pj  = pl & 7;

    __shared__ _Float16 ksm[196 * KVSTR]; // 15.7 KB, K only

    const size_t hb = (size_t)(b * 4 + h) * NPIX * 32;
    const _Float16* kbase = kb + hb;
    const _Float16* vbase = vb + hb;

    // ---- stage K: 784 16B-granules over 256 threads ----
    for (int e = t; e < 196 * 4; e += 256) {
        int p = e >> 2;
        int g = e & 3;
        int wi = p / 14;
        int wj = p - wi * 14;
        int gi = ti - 3 + wi;
        int gj = tj - 3 + wj;
        half8 kv = (half8){0,0,0,0,0,0,0,0};
        if (((unsigned)gi < 56u) && ((unsigned)gj < 56u))
            kv = *reinterpret_cast<const half8*>(kbase + (gi * 56 + gj) * 32 + g * 8);
        *reinterpret_cast<half8*>(&ksm[p * KVSTR + g * 8]) = kv;
    }

    // ---- load this lane's q d-slice while K staging is in flight ----
    const int pix = (ti + pi) * 56 + (tj + pj);
    half8 qv = *reinterpret_cast<const half8*>(qb + hb + (size_t)pix * 32 + sub * 8);

    __syncthreads();

    // ---- QK^T + bias (K from LDS) ----
    const float* bias = rpb + h * 169;
    float logits[49];
    float m = -1e30f;
#pragma unroll
    for (int ki = 0; ki < 7; ++ki) {
#pragma unroll
        for (int kj = 0; kj < 7; ++kj) {
            int nb = (pi + ki) * 14 + (pj + kj);
            half8 kk = *reinterpret_cast<const half8*>(&ksm[nb * KVSTR + sub * 8]);
            float s = dot8h(qv, kk, 0.f);
            s = quad_reduce_sum(s);       // full 32-d dot in all 4 lanes
            float lg = s * SCALE + bias[(ki + 3) * 13 + (kj + 3)];
            logits[ki * 7 + kj] = lg;
            m = fmaxf(m, lg);
        }
    }

    // ---- softmax (redundant per quad lane; cheap) ----
    float sum = 0.f;
#pragma unroll
    for (int n = 0; n < 49; ++n) {
        float e = __expf(logits[n] - m);
        logits[n] = e;
        sum += e;
    }
    float inv = 1.f / sum;

    // ---- P·V: V direct from global (L1-resident halo, coalesced across pj) ----
    float o[8] = {0.f, 0.f, 0.f, 0.f, 0.f, 0.f, 0.f, 0.f};
#pragma unroll
    for (int ki = 0; ki < 7; ++ki) {
        const int gi = ti + pi - 3 + ki;
#pragma unroll
        for (int kj = 0; kj < 7; ++kj) {
            const int gj = tj + pj - 3 + kj;
            if (((unsigned)gi < 56u) && ((unsigned)gj < 56u)) {
                half8 vv = *reinterpret_cast<const half8*>(
                    vbase + (gi * 56 + gj) * 32 + sub * 8);
                float wgt = logits[ki * 7 + kj];
#pragma unroll
                for (int i = 0; i < 8; ++i)
                    o[i] += wgt * (float)vv[i];
            }
        }
    }

    // ---- write fp16 att, layout [b][pix][h*32+d] for the proj GEMM ----
    _Float16* dst = att + ((size_t)b * NPIX + pix) * 128 + h * 32 + sub * 8;
    half8 r;
#pragma unroll
    for (int i = 0; i < 8; ++i) r[i] = (_Float16)(o[i] * inv);
    *reinterpret_cast<half8*>(dst) = r;
}

// ---------------------------------------------------------------------------
extern "C" void kernel_launch(void* const* d_in, const int* in_sizes, int n_in,
                              void* d_out, int out_size, void* d_ws, size_t ws_size,
                              hipStream_t stream)
{
    const float* x      = (const float*)d_in[0];
    const float* qkv_w  = (const float*)d_in[1];
    const float* qkv_b  = (const float*)d_in[2];
    const float* rpb    = (const float*)d_in[3];
    const float* proj_w = (const float*)d_in[4];
    const float* proj_b = (const float*)d_in[5];
    float* out = (float*)d_out;

    // ws layout (fp16): q | k | v | att  (3.2 MB each, 12.8 MB total)
    _Float16* qbuf = (_Float16*)d_ws;
    _Float16* kbuf = qbuf + (size_t)QKV_STRIDE;
    _Float16* vbuf = kbuf + (size_t)QKV_STRIDE;
    _Float16* att  = vbuf + (size_t)QKV_STRIDE;

    // 1) QKV projection: [12544,128] @ [384,128]^T -> fp16 q/k/v scatter
    //    BM=64 BN=128, 2x2 waves, grid 196x3
    gemm_mfma<0, 64, 128, 2, 2><<<dim3(196, 3), dim3(256), 0, stream>>>(
        x, qkv_w, qkv_b, qbuf);

    // 2) neighborhood attention: 784 blocks x 4 waves, fp16 in/out
    natten_k<<<dim3(49, 4, 4), dim3(256), 0, stream>>>(qbuf, kbuf, vbuf, rpb, att);

    // 3) output projection: [12544,128] @ [128,128]^T, fp16 A -> fp32 out
    //    BM=16 BN=128, 1x4 waves, grid 784
    gemm_mfma<1, 16, 128, 1, 4><<<dim3(784, 1), dim3(256), 0, stream>>>(
        att, proj_w, proj_b, out);
}

// Round 7
// 37.834 us; speedup vs baseline: 1.3766x; 1.1124x over previous
//
#include <hip/hip_runtime.h>

#define NPIX   3136        // 56*56
#define MROWS  12544       // 4*3136
#define QKV_STRIDE 1605632 // MROWS*128 halves per q/k/v buffer
#define SCALE  0.17677669529663687f  // 32^-0.5

typedef __attribute__((ext_vector_type(8))) _Float16 half8;
typedef __attribute__((ext_vector_type(2))) _Float16 v2h;
typedef __attribute__((ext_vector_type(4))) float    f32x4;

#if defined(__has_builtin)
#if __has_builtin(__builtin_amdgcn_fdot2)
#define HAS_FDOT2 1
#endif
#endif

// sum across each aligned quad of 4 lanes via DPP quad_perm
__device__ __forceinline__ float quad_reduce_sum(float x) {
    x += __int_as_float(__builtin_amdgcn_mov_dpp(__float_as_int(x), 0xB1, 0xF, 0xF, true));
    x += __int_as_float(__builtin_amdgcn_mov_dpp(__float_as_int(x), 0x4E, 0xF, 0xF, true));
    return x;
}

// 8-wide fp16 dot with fp32 accumulate (v_dot2_f32_f16 x4)
__device__ __forceinline__ float dot8h(half8 a, half8 b, float acc) {
#ifdef HAS_FDOT2
    union { half8 v; v2h p[4]; } ua, ub;
    ua.v = a; ub.v = b;
    acc = __builtin_amdgcn_fdot2(ua.p[0], ub.p[0], acc, false);
    acc = __builtin_amdgcn_fdot2(ua.p[1], ub.p[1], acc, false);
    acc = __builtin_amdgcn_fdot2(ua.p[2], ub.p[2], acc, false);
    acc = __builtin_amdgcn_fdot2(ua.p[3], ub.p[3], acc, false);
#else
#pragma unroll
    for (int i = 0; i < 8; ++i) acc += (float)a[i] * (float)b[i];
#endif
    return acc;
}

// ---------------------------------------------------------------------------
// MFMA GEMM (round-4-validated structure): out = A[M][128]*W[N][128]^T + bias,
// fp16 MFMA / fp32 accum. Full K=128 staged once in LDS; XOR swizzle
// k ^ ((r&7)<<3) on a [rows][128]-half layout.
// Round-7 config change only: QKV 64x64 tiles (1176 blocks, 4.6/CU, 32KB LDS)
// and proj 32x64 tiles (784 blocks, 24KB LDS) — the kernel is latency-bound
// on its stage->barrier->compute chain, so resident-block count is the lever
// (round-5 lesson: do NOT drop the LDS staging itself).
// Fragment maps (16x16x32): A: m=l&15, k=(l>>4)*8+i; B mirrored;
// D: col=l&15, row=(l>>4)*4+reg  [m89-verified, validated rounds 3-6].
// EPI=0: A fp32, scatter fp16 q/k/v [which][b*4+head][pix][32]
// EPI=1: A fp16 (att), write fp32 out[row][128]
// ---------------------------------------------------------------------------
template<int EPI, int BM, int BN, int WM, int WN>
__global__ __launch_bounds__(256)
void gemm_mfma(const void* __restrict__ Av, const float* __restrict__ W,
               const float* __restrict__ bias, void* __restrict__ outv)
{
    constexpr int WTM = BM / WM;
    constexpr int WTN = BN / WN;
    constexpr int FM  = WTM / 16;
    constexpr int FN  = WTN / 16;
    const int row0 = blockIdx.x * BM;
    const int col0 = blockIdx.y * BN;
    const int t  = threadIdx.x;
    const int w  = t >> 6;
    const int l  = t & 63;
    const int wm = w / WN;
    const int wn = w % WN;

    __shared__ _Float16 Ah[BM * 128];
    __shared__ _Float16 Wh[BN * 128];

    // ---- stage A ----
    if (EPI == 0) {
        const float* A = (const float*)Av;
        constexpr int AIT = BM * 32 / 256;          // float4s per thread
#pragma unroll
        for (int it = 0; it < AIT; ++it) {
            int idx = t + it * 256;
            int r = idx >> 5, k0 = (idx & 31) << 2; // k0 in halves (4-half granule)
            float4 v = *reinterpret_cast<const float4*>(A + (size_t)(row0 + r) * 128 + k0);
            union { _Float16 h[4]; uint2 u; } cv;
            cv.h[0] = (_Float16)v.x; cv.h[1] = (_Float16)v.y;
            cv.h[2] = (_Float16)v.z; cv.h[3] = (_Float16)v.w;
            *reinterpret_cast<uint2*>(&Ah[r * 128 + (k0 ^ ((r & 7) << 3))]) = cv.u;
        }
    } else {
        const _Float16* A = (const _Float16*)Av;
        constexpr int AIT = BM * 16 / 256;          // half8s per thread
#pragma unroll
        for (int it = 0; it < AIT; ++it) {
            int idx = t + it * 256;
            int r = idx >> 4, k0 = (idx & 15) << 3; // k0 in halves (8-half granule)
            half8 v = *reinterpret_cast<const half8*>(A + (size_t)(row0 + r) * 128 + k0);
            *reinterpret_cast<half8*>(&Ah[r * 128 + (k0 ^ ((r & 7) << 3))]) = v;
        }
    }
    // ---- stage W (fp32 global -> fp16 LDS) ----
    {
        constexpr int WIT = BN * 32 / 256;
#pragma unroll
        for (int it = 0; it < WIT; ++it) {
            int idx = t + it * 256;
            int r = idx >> 5, k0 = (idx & 31) << 2;
            float4 v = *reinterpret_cast<const float4*>(W + (size_t)(col0 + r) * 128 + k0);
            union { _Float16 h[4]; uint2 u; } cv;
            cv.h[0] = (_Float16)v.x; cv.h[1] = (_Float16)v.y;
            cv.h[2] = (_Float16)v.z; cv.h[3] = (_Float16)v.w;
            *reinterpret_cast<uint2*>(&Wh[r * 128 + (k0 ^ ((r & 7) << 3))]) = cv.u;
        }
    }
    __syncthreads();

    f32x4 acc[FM][FN];
#pragma unroll
    for (int mf = 0; mf < FM; ++mf)
#pragma unroll
        for (int nf = 0; nf < FN; ++nf) acc[mf][nf] = (f32x4){0.f, 0.f, 0.f, 0.f};

#pragma unroll
    for (int ks = 0; ks < 4; ++ks) {
        const int kb = ks * 32 + ((l >> 4) << 3);
        half8 a[FM], b[FN];
#pragma unroll
        for (int mf = 0; mf < FM; ++mf) {
            int m = wm * WTM + mf * 16 + (l & 15);
            a[mf] = *reinterpret_cast<const half8*>(&Ah[m * 128 + (kb ^ ((m & 7) << 3))]);
        }
#pragma unroll
        for (int nf = 0; nf < FN; ++nf) {
            int n = wn * WTN + nf * 16 + (l & 15);
            b[nf] = *reinterpret_cast<const half8*>(&Wh[n * 128 + (kb ^ ((n & 7) << 3))]);
        }
#pragma unroll
        for (int mf = 0; mf < FM; ++mf)
#pragma unroll
            for (int nf = 0; nf < FN; ++nf)
                acc[mf][nf] = __builtin_amdgcn_mfma_f32_16x16x32_f16(
                    a[mf], b[nf], acc[mf][nf], 0, 0, 0);
    }

    // ---- epilogue ----
#pragma unroll
    for (int mf = 0; mf < FM; ++mf) {
#pragma unroll
        for (int nf = 0; nf < FN; ++nf) {
#pragma unroll
            for (int r = 0; r < 4; ++r) {
                int row = row0 + wm * WTM + mf * 16 + ((l >> 4) << 2) + r;
                int col = col0 + wn * WTN + nf * 16 + (l & 15);
                float val = acc[mf][nf][r] + bias[col];
                if (EPI == 1) {
                    ((float*)outv)[(size_t)row * 128 + col] = val;
                } else {
                    int b_  = row / NPIX;
                    int pix = row - b_ * NPIX;
                    int which = col >> 7;          // 0=q 1=k 2=v
                    int head  = (col & 127) >> 5;
                    int d     = col & 31;
                    ((_Float16*)outv)[(size_t)which * QKV_STRIDE +
                        ((size_t)(b_ * 4 + head) * NPIX + pix) * 32 + d] = (_Float16)val;
                }
            }
        }
    }
}

// ---------------------------------------------------------------------------
// Neighborhood attention, fp16 data / fp32 accum (round-4 structure + single
// barrier). 256-thread block per (8x8 tile, head, batch); 4 lanes per pixel,
// 8-half d-slice each; quad logit reduce via DPP.
// Round-6 lesson: V direct-from-global regressed 7us (49 conditional per-lane
// L2 loads can't be hidden at 3 waves/SIMD; L1 thrash). Both K and V stay in
// LDS. New here: V gets its OWN buffer and is staged immediately after K
// (both load streams in flight together), so ONE barrier covers everything —
// round 4 paid 3 barriers and exposed V-staging latency mid-kernel.
// OOB neighbors stay zero -> logit = bias only, kept in softmax (matches
// reference zero-padding semantics).
// ---------------------------------------------------------------------------
#define KVSTR 40
__global__ __launch_bounds__(256, 3)
void natten_k(const _Float16* __restrict__ qb, const _Float16* __restrict__ kb,
              const _Float16* __restrict__ vb, const float* __restrict__ rpb,
              _Float16* __restrict__ att)
{
    const int tile = blockIdx.x;          // 0..48
    const int h    = blockIdx.y;          // 0..3
    const int b    = blockIdx.z;          // 0..3
    const int ti = (tile / 7) * 8;
    const int tj = (tile % 7) * 8;
    const int t   = threadIdx.x;
    const int sub = t & 3;                // d-slice owner within the quad
    const int pl  = t >> 2;               // 0..63 local pixel
    const int pi  = pl >> 3;
    const int pj  = pl & 7;

    __shared__ _Float16 ksm[196 * KVSTR]; // 15.7 KB
    __shared__ _Float16 vsm[196 * KVSTR]; // 15.7 KB

    const size_t hb = (size_t)(b * 4 + h) * NPIX * 32;
    const _Float16* kbase = kb + hb;
    const _Float16* vbase = vb + hb;

    // ---- stage K and V back-to-back (both load streams in flight) ----
    for (int e = t; e < 196 * 4; e += 256) {
        int p = e >> 2;
        int g = e & 3;
        int wi = p / 14;
        int wj = p - wi * 14;
        int gi = ti - 3 + wi;
        int gj = tj - 3 + wj;
        bool ok = ((unsigned)gi < 56u) && ((unsigned)gj < 56u);
        half8 kv = (half8){0,0,0,0,0,0,0,0};
        if (ok) kv = *reinterpret_cast<const half8*>(kbase + (gi * 56 + gj) * 32 + g * 8);
        *reinterpret_cast<half8*>(&ksm[p * KVSTR + g * 8]) = kv;
        half8 vv = (half8){0,0,0,0,0,0,0,0};
        if (ok) vv = *reinterpret_cast<const half8*>(vbase + (gi * 56 + gj) * 32 + g * 8);
        *reinterpret_cast<half8*>(&vsm[p * KVSTR + g * 8]) = vv;
    }

    // ---- load this lane's q d-slice while staging is in flight ----
    const int pix = (ti + pi) * 56 + (tj + pj);
    half8 qv = *reinterpret_cast<const half8*>(qb + hb + (size_t)pix * 32 + sub * 8);

    __syncthreads();   // the ONLY barrier

    // ---- QK^T + bias (K from LDS) ----
    const float* bias = rpb + h * 169;
    float logits[49];
    float m = -1e30f;
#pragma unroll
    for (int ki = 0; ki < 7; ++ki) {
#pragma unroll
        for (int kj = 0; kj < 7; ++kj) {
            int nb = (pi + ki) * 14 + (pj + kj);
            half8 kk = *reinterpret_cast<const half8*>(&ksm[nb * KVSTR + sub * 8]);
            float s = dot8h(qv, kk, 0.f);
            s = quad_reduce_sum(s);       // full 32-d dot in all 4 lanes
            float lg = s * SCALE + bias[(ki + 3) * 13 + (kj + 3)];
            logits[ki * 7 + kj] = lg;
            m = fmaxf(m, lg);
        }
    }

    // ---- softmax (redundant per quad lane; cheap) ----
    float sum = 0.f;
#pragma unroll
    for (int n = 0; n < 49; ++n) {
        float e = __expf(logits[n] - m);
        logits[n] = e;
        sum += e;
    }
    float inv = 1.f / sum;

    // ---- P·V (V from LDS, fp32 accum) ----
    float o[8] = {0.f, 0.f, 0.f, 0.f, 0.f, 0.f, 0.f, 0.f};
#pragma unroll
    for (int ki = 0; ki < 7; ++ki) {
#pragma unroll
        for (int kj = 0; kj < 7; ++kj) {
            int nb = (pi + ki) * 14 + (pj + kj);
            half8 vv = *reinterpret_cast<const half8*>(&vsm[nb * KVSTR + sub * 8]);
            float wgt = logits[ki * 7 + kj];
#pragma unroll
            for (int i = 0; i < 8; ++i)
                o[i] += wgt * (float)vv[i];
        }
    }

    // ---- write fp16 att, layout [b][pix][h*32+d] for the proj GEMM ----
    _Float16* dst = att + ((size_t)b * NPIX + pix) * 128 + h * 32 + sub * 8;
    half8 r;
#pragma unroll
    for (int i = 0; i < 8; ++i) r[i] = (_Float16)(o[i] * inv);
    *reinterpret_cast<half8*>(dst) = r;
}

// ---------------------------------------------------------------------------
extern "C" void kernel_launch(void* const* d_in, const int* in_sizes, int n_in,
                              void* d_out, int out_size, void* d_ws, size_t ws_size,
                              hipStream_t stream)
{
    const float* x      = (const float*)d_in[0];
    const float* qkv_w  = (const float*)d_in[1];
    const float* qkv_b  = (const float*)d_in[2];
    const float* rpb    = (const float*)d_in[3];
    const float* proj_w = (const float*)d_in[4];
    const float* proj_b = (const float*)d_in[5];
    float* out = (float*)d_out;

    // ws layout (fp16): q | k | v | att  (3.2 MB each, 12.8 MB total)
    _Float16* qbuf = (_Float16*)d_ws;
    _Float16* kbuf = qbuf + (size_t)QKV_STRIDE;
    _Float16* vbuf = kbuf + (size_t)QKV_STRIDE;
    _Float16* att  = vbuf + (size_t)QKV_STRIDE;

    // 1) QKV projection: [12544,128] @ [384,128]^T -> fp16 q/k/v scatter
    //    BM=64 BN=64 (2x2 waves, wave tile 32x32, 16 MFMA), grid 196x6
    //    = 1176 blocks, 32KB LDS -> ~4.6 blocks/CU
    gemm_mfma<0, 64, 64, 2, 2><<<dim3(196, 6), dim3(256), 0, stream>>>(
        x, qkv_w, qkv_b, qbuf);

    // 2) neighborhood attention: 784 blocks x 4 waves, single-barrier
    natten_k<<<dim3(49, 4, 4), dim3(256), 0, stream>>>(qbuf, kbuf, vbuf, rpb, att);

    // 3) output projection: [12544,128] @ [128,128]^T, fp16 A -> fp32 out
    //    BM=32 BN=64 (2x2 waves, wave tile 16x32, 8 MFMA), grid 392x2
    //    = 784 blocks, 24KB LDS
    gemm_mfma<1, 32, 64, 2, 2><<<dim3(392, 2), dim3(256), 0, stream>>>(
        att, proj_w, proj_b, out);
}

// Round 8
// 35.765 us; speedup vs baseline: 1.4562x; 1.0578x over previous
//
#include <hip/hip_runtime.h>

#define NPIX   3136        // 56*56
#define MROWS  12544       // 4*3136
#define QKV_STRIDE 1605632 // MROWS*128 halves per q/k/v buffer
#define SCALE  0.17677669529663687f  // 32^-0.5

typedef __attribute__((ext_vector_type(8))) _Float16 half8;
typedef __attribute__((ext_vector_type(2))) _Float16 v2h;
typedef __attribute__((ext_vector_type(4))) float    f32x4;

#if defined(__has_builtin)
#if __has_builtin(__builtin_amdgcn_fdot2)
#define HAS_FDOT2 1
#endif
#endif

// sum across each aligned quad of 4 lanes via DPP quad_perm
__device__ __forceinline__ float quad_reduce_sum(float x) {
    x += __int_as_float(__builtin_amdgcn_mov_dpp(__float_as_int(x), 0xB1, 0xF, 0xF, true));
    x += __int_as_float(__builtin_amdgcn_mov_dpp(__float_as_int(x), 0x4E, 0xF, 0xF, true));
    return x;
}

// 8-wide fp16 dot with fp32 accumulate (v_dot2_f32_f16 x4)
__device__ __forceinline__ float dot8h(half8 a, half8 b, float acc) {
#ifdef HAS_FDOT2
    union { half8 v; v2h p[4]; } ua, ub;
    ua.v = a; ub.v = b;
    acc = __builtin_amdgcn_fdot2(ua.p[0], ub.p[0], acc, false);
    acc = __builtin_amdgcn_fdot2(ua.p[1], ub.p[1], acc, false);
    acc = __builtin_amdgcn_fdot2(ua.p[2], ub.p[2], acc, false);
    acc = __builtin_amdgcn_fdot2(ua.p[3], ub.p[3], acc, false);
#else
#pragma unroll
    for (int i = 0; i < 8; ++i) acc += (float)a[i] * (float)b[i];
#endif
    return acc;
}

// ---------------------------------------------------------------------------
// MFMA GEMM — EXACT round-4 configuration (best-known: 34.9us total).
// out = A[M][128]*W[N][128]^T + bias, fp16 MFMA / fp32 accum. Full K=128
// staged once in LDS; XOR swizzle k ^ ((r&7)<<3) on [rows][128]-half layout.
// Round-7 lesson: shrinking tiles (QKV 64x64, proj 32x64) to raise resident
// blocks REGRESSED ~3us — each extra block adds a full stage->barrier chain
// that doesn't pack; bigger tiles amortize staging better. Round-5 lesson:
// don't drop LDS staging. Tile config is now pinned at R4's.
// Fragment maps (16x16x32): A: m=l&15, k=(l>>4)*8+i; B mirrored;
// D: col=l&15, row=(l>>4)*4+reg  [m89-verified, validated rounds 3-7].
// EPI=0: A fp32, scatter fp16 q/k/v [which][b*4+head][pix][32]
// EPI=1: A fp16 (att), write fp32 out[row][128]
// ---------------------------------------------------------------------------
template<int EPI, int BM, int BN, int WM, int WN>
__global__ __launch_bounds__(256)
void gemm_mfma(const void* __restrict__ Av, const float* __restrict__ W,
               const float* __restrict__ bias, void* __restrict__ outv)
{
    constexpr int WTM = BM / WM;
    constexpr int WTN = BN / WN;
    constexpr int FM  = WTM / 16;
    constexpr int FN  = WTN / 16;
    const int row0 = blockIdx.x * BM;
    const int col0 = blockIdx.y * BN;
    const int t  = threadIdx.x;
    const int w  = t >> 6;
    const int l  = t & 63;
    const int wm = w / WN;
    const int wn = w % WN;

    __shared__ _Float16 Ah[BM * 128];
    __shared__ _Float16 Wh[BN * 128];

    // ---- stage A ----
    if (EPI == 0) {
        const float* A = (const float*)Av;
        constexpr int AIT = BM * 32 / 256;          // float4s per thread
#pragma unroll
        for (int it = 0; it < AIT; ++it) {
            int idx = t + it * 256;
            int r = idx >> 5, k0 = (idx & 31) << 2; // k0 in halves (4-half granule)
            float4 v = *reinterpret_cast<const float4*>(A + (size_t)(row0 + r) * 128 + k0);
            union { _Float16 h[4]; uint2 u; } cv;
            cv.h[0] = (_Float16)v.x; cv.h[1] = (_Float16)v.y;
            cv.h[2] = (_Float16)v.z; cv.h[3] = (_Float16)v.w;
            *reinterpret_cast<uint2*>(&Ah[r * 128 + (k0 ^ ((r & 7) << 3))]) = cv.u;
        }
    } else {
        const _Float16* A = (const _Float16*)Av;
        constexpr int AIT = BM * 16 / 256;          // half8s per thread
#pragma unroll
        for (int it = 0; it < AIT; ++it) {
            int idx = t + it * 256;
            int r = idx >> 4, k0 = (idx & 15) << 3; // k0 in halves (8-half granule)
            half8 v = *reinterpret_cast<const half8*>(A + (size_t)(row0 + r) * 128 + k0);
            *reinterpret_cast<half8*>(&Ah[r * 128 + (k0 ^ ((r & 7) << 3))]) = v;
        }
    }
    // ---- stage W (fp32 global -> fp16 LDS) ----
    {
        constexpr int WIT = BN * 32 / 256;
#pragma unroll
        for (int it = 0; it < WIT; ++it) {
            int idx = t + it * 256;
            int r = idx >> 5, k0 = (idx & 31) << 2;
            float4 v = *reinterpret_cast<const float4*>(W + (size_t)(col0 + r) * 128 + k0);
            union { _Float16 h[4]; uint2 u; } cv;
            cv.h[0] = (_Float16)v.x; cv.h[1] = (_Float16)v.y;
            cv.h[2] = (_Float16)v.z; cv.h[3] = (_Float16)v.w;
            *reinterpret_cast<uint2*>(&Wh[r * 128 + (k0 ^ ((r & 7) << 3))]) = cv.u;
        }
    }
    __syncthreads();

    f32x4 acc[FM][FN];
#pragma unroll
    for (int mf = 0; mf < FM; ++mf)
#pragma unroll
        for (int nf = 0; nf < FN; ++nf) acc[mf][nf] = (f32x4){0.f, 0.f, 0.f, 0.f};

#pragma unroll
    for (int ks = 0; ks < 4; ++ks) {
        const int kb = ks * 32 + ((l >> 4) << 3);
        half8 a[FM], b[FN];
#pragma unroll
        for (int mf = 0; mf < FM; ++mf) {
            int m = wm * WTM + mf * 16 + (l & 15);
            a[mf] = *reinterpret_cast<const half8*>(&Ah[m * 128 + (kb ^ ((m & 7) << 3))]);
        }
#pragma unroll
        for (int nf = 0; nf < FN; ++nf) {
            int n = wn * WTN + nf * 16 + (l & 15);
            b[nf] = *reinterpret_cast<const half8*>(&Wh[n * 128 + (kb ^ ((n & 7) << 3))]);
        }
#pragma unroll
        for (int mf = 0; mf < FM; ++mf)
#pragma unroll
            for (int nf = 0; nf < FN; ++nf)
                acc[mf][nf] = __builtin_amdgcn_mfma_f32_16x16x32_f16(
                    a[mf], b[nf], acc[mf][nf], 0, 0, 0);
    }

    // ---- epilogue ----
#pragma unroll
    for (int mf = 0; mf < FM; ++mf) {
#pragma unroll
        for (int nf = 0; nf < FN; ++nf) {
#pragma unroll
            for (int r = 0; r < 4; ++r) {
                int row = row0 + wm * WTM + mf * 16 + ((l >> 4) << 2) + r;
                int col = col0 + wn * WTN + nf * 16 + (l & 15);
                float val = acc[mf][nf][r] + bias[col];
                if (EPI == 1) {
                    ((float*)outv)[(size_t)row * 128 + col] = val;
                } else {
                    int b_  = row / NPIX;
                    int pix = row - b_ * NPIX;
                    int which = col >> 7;          // 0=q 1=k 2=v
                    int head  = (col & 127) >> 5;
                    int d     = col & 31;
                    ((_Float16*)outv)[(size_t)which * QKV_STRIDE +
                        ((size_t)(b_ * 4 + head) * NPIX + pix) * 32 + d] = (_Float16)val;
                }
            }
        }
    }
}

// ---------------------------------------------------------------------------
// Neighborhood attention, fp16 data / fp32 accum (single-barrier form — the
// ONE delta vs the round-4 34.9us baseline). 256-thread block per (8x8 tile,
// head, batch); 4 lanes per pixel, 8-half d-slice each; quad logit reduce
// via DPP. K and V staged back-to-back into separate LDS buffers (both load
// streams in flight), ONE __syncthreads total.
// Bank math: stride 40 halves -> quad-index (5nb+2sub) mod 8 cycles all 8
// quads over consecutive nb; 8 accesses/quad = the wave64-b128 floor
// (stride 32 was also at floor — R5's "conflict fix" was a non-issue).
// Round-6 lesson: V direct-from-global regresses (unhidden L2 latency, L1
// thrash); both operands stay in LDS.
// OOB neighbors stay zero -> logit = bias only, kept in softmax (matches
// reference zero-padding semantics).
// ---------------------------------------------------------------------------
#define KVSTR 40
__global__ __launch_bounds__(256, 3)
void natten_k(const _Float16* __restrict__ qb, const _Float16* __restrict__ kb,
              const _Float16* __restrict__ vb, const float* __restrict__ rpb,
              _Float16* __restrict__ att)
{
    const int tile = blockIdx.x;          // 0..48
    const int h    = blockIdx.y;          // 0..3
    const int b    = blockIdx.z;          // 0..3
    const int ti = (tile / 7) * 8;
    const int tj = (tile % 7) * 8;
    const int t   = threadIdx.x;
    const int sub = t & 3;                // d-slice owner within the quad
    const int pl  = t >> 2;               // 0..63 local pixel
    const int pi  = pl >> 3;
    const int pj  = pl & 7;

    __shared__ _Float16 ksm[196 * KVSTR]; // 15.7 KB
    __shared__ _Float16 vsm[196 * KVSTR]; // 15.7 KB

    const size_t hb = (size_t)(b * 4 + h) * NPIX * 32;
    const _Float16* kbase = kb + hb;
    const _Float16* vbase = vb + hb;

    // ---- stage K and V back-to-back (both load streams in flight) ----
    for (int e = t; e < 196 * 4; e += 256) {
        int p = e >> 2;
        int g = e & 3;
        int wi = p / 14;
        int wj = p - wi * 14;
        int gi = ti - 3 + wi;
        int gj = tj - 3 + wj;
        bool ok = ((unsigned)gi < 56u) && ((unsigned)gj < 56u);
        half8 kv = (half8){0,0,0,0,0,0,0,0};
        if (ok) kv = *reinterpret_cast<const half8*>(kbase + (gi * 56 + gj) * 32 + g * 8);
        *reinterpret_cast<half8*>(&ksm[p * KVSTR + g * 8]) = kv;
        half8 vv = (half8){0,0,0,0,0,0,0,0};
        if (ok) vv = *reinterpret_cast<const half8*>(vbase + (gi * 56 + gj) * 32 + g * 8);
        *reinterpret_cast<half8*>(&vsm[p * KVSTR + g * 8]) = vv;
    }

    // ---- load this lane's q d-slice while staging is in flight ----
    const int pix = (ti + pi) * 56 + (tj + pj);
    half8 qv = *reinterpret_cast<const half8*>(qb + hb + (size_t)pix * 32 + sub * 8);

    __syncthreads();   // the ONLY barrier

    // ---- QK^T + bias (K from LDS) ----
    const float* bias = rpb + h * 169;
    float logits[49];
    float m = -1e30f;
#pragma unroll
    for (int ki = 0; ki < 7; ++ki) {
#pragma unroll
        for (int kj = 0; kj < 7; ++kj) {
            int nb = (pi + ki) * 14 + (pj + kj);
            half8 kk = *reinterpret_cast<const half8*>(&ksm[nb * KVSTR + sub * 8]);
            float s = dot8h(qv, kk, 0.f);
            s = quad_reduce_sum(s);       // full 32-d dot in all 4 lanes
            float lg = s * SCALE + bias[(ki + 3) * 13 + (kj + 3)];
            logits[ki * 7 + kj] = lg;
            m = fmaxf(m, lg);
        }
    }

    // ---- softmax (redundant per quad lane; cheap) ----
    float sum = 0.f;
#pragma unroll
    for (int n = 0; n < 49; ++n) {
        float e = __expf(logits[n] - m);
        logits[n] = e;
        sum += e;
    }
    float inv = 1.f / sum;

    // ---- P·V (V from LDS, fp32 accum) ----
    float o[8] = {0.f, 0.f, 0.f, 0.f, 0.f, 0.f, 0.f, 0.f};
#pragma unroll
    for (int ki = 0; ki < 7; ++ki) {
#pragma unroll
        for (int kj = 0; kj < 7; ++kj) {
            int nb = (pi + ki) * 14 + (pj + kj);
            half8 vv = *reinterpret_cast<const half8*>(&vsm[nb * KVSTR + sub * 8]);
            float wgt = logits[ki * 7 + kj];
#pragma unroll
            for (int i = 0; i < 8; ++i)
                o[i] += wgt * (float)vv[i];
        }
    }

    // ---- write fp16 att, layout [b][pix][h*32+d] for the proj GEMM ----
    _Float16* dst = att + ((size_t)b * NPIX + pix) * 128 + h * 32 + sub * 8;
    half8 r;
#pragma unroll
    for (int i = 0; i < 8; ++i) r[i] = (_Float16)(o[i] * inv);
    *reinterpret_cast<half8*>(dst) = r;
}

// ---------------------------------------------------------------------------
extern "C" void kernel_launch(void* const* d_in, const int* in_sizes, int n_in,
                              void* d_out, int out_size, void* d_ws, size_t ws_size,
                              hipStream_t stream)
{
    const float* x      = (const float*)d_in[0];
    const float* qkv_w  = (const float*)d_in[1];
    const float* qkv_b  = (const float*)d_in[2];
    const float* rpb    = (const float*)d_in[3];
    const float* proj_w = (const float*)d_in[4];
    const float* proj_b = (const float*)d_in[5];
    float* out = (float*)d_out;

    // ws layout (fp16): q | k | v | att  (3.2 MB each, 12.8 MB total)
    _Float16* qbuf = (_Float16*)d_ws;
    _Float16* kbuf = qbuf + (size_t)QKV_STRIDE;
    _Float16* vbuf = kbuf + (size_t)QKV_STRIDE;
    _Float16* att  = vbuf + (size_t)QKV_STRIDE;

    // 1) QKV projection: [12544,128] @ [384,128]^T -> fp16 q/k/v scatter
    //    R4 config: BM=64 BN=128, 2x2 waves, grid 196x3 (48KB LDS, 3 blk/CU)
    gemm_mfma<0, 64, 128, 2, 2><<<dim3(196, 3), dim3(256), 0, stream>>>(
        x, qkv_w, qkv_b, qbuf);

    // 2) neighborhood attention: 784 blocks x 4 waves, single-barrier
    natten_k<<<dim3(49, 4, 4), dim3(256), 0, stream>>>(qbuf, kbuf, vbuf, rpb, att);

    // 3) output projection: [12544,128] @ [128,128]^T, fp16 A -> fp32 out
    //    R4 config: BM=16 BN=128, 1x4 waves, grid 784 (36KB LDS)
    gemm_mfma<1, 16, 128, 1, 4><<<dim3(784, 1), dim3(256), 0, stream>>>(
        att, proj_w, proj_b, out);
}

// Round 9
// 34.562 us; speedup vs baseline: 1.5069x; 1.0348x over previous
//
#include <hip/hip_runtime.h>

#define NPIX   3136        // 56*56
#define MROWS  12544       // 4*3136
#define QKV_STRIDE 1605632 // MROWS*128 halves per q/k/v buffer
#define SCALE  0.17677669529663687f  // 32^-0.5
#define KVS    136         // LDS row stride (halves): 17 granules, odd -> even bank spread
#define HP     140         // halo pixels per fused block (14 x 10)

typedef __attribute__((ext_vector_type(8))) _Float16 half8;
typedef __attribute__((ext_vector_type(2))) _Float16 v2h;
typedef __attribute__((ext_vector_type(4))) float    f32x4;

#if defined(__has_builtin)
#if __has_builtin(__builtin_amdgcn_fdot2)
#define HAS_FDOT2 1
#endif
#endif

// sum across each aligned quad of 4 lanes via DPP quad_perm
__device__ __forceinline__ float quad_reduce_sum(float x) {
    x += __int_as_float(__builtin_amdgcn_mov_dpp(__float_as_int(x), 0xB1, 0xF, 0xF, true));
    x += __int_as_float(__builtin_amdgcn_mov_dpp(__float_as_int(x), 0x4E, 0xF, 0xF, true));
    return x;
}

// 8-wide fp16 dot with fp32 accumulate (v_dot2_f32_f16 x4)
__device__ __forceinline__ float dot8h(half8 a, half8 b, float acc) {
#ifdef HAS_FDOT2
    union { half8 v; v2h p[4]; } ua, ub;
    ua.v = a; ub.v = b;
    acc = __builtin_amdgcn_fdot2(ua.p[0], ub.p[0], acc, false);
    acc = __builtin_amdgcn_fdot2(ua.p[1], ub.p[1], acc, false);
    acc = __builtin_amdgcn_fdot2(ua.p[2], ub.p[2], acc, false);
    acc = __builtin_amdgcn_fdot2(ua.p[3], ub.p[3], acc, false);
#else
#pragma unroll
    for (int i = 0; i < 8; ++i) acc += (float)a[i] * (float)b[i];
#endif
    return acc;
}

__device__ __forceinline__ half8 cvt8(float4 a, float4 b) {
    half8 r;
    r[0] = (_Float16)a.x; r[1] = (_Float16)a.y;
    r[2] = (_Float16)a.z; r[3] = (_Float16)a.w;
    r[4] = (_Float16)b.x; r[5] = (_Float16)b.y;
    r[6] = (_Float16)b.z; r[7] = (_Float16)b.w;
    return r;
}

// ---------------------------------------------------------------------------
// QKV GEMM — R4-validated structure/config. out = x[M][128]*W[384][128]^T+bias,
// fp16 MFMA / fp32 accum, full K=128 staged once in LDS, XOR swizzle
// k ^ ((r&7)<<3). ONLY change vs R8: scatter layout is now head-contiguous
// [which][b][pix][128] so the fused attention kernel can stage whole 256B
// pixel rows for all 4 heads at once.
// Fragment maps (16x16x32): A: m=l&15, k=(l>>4)*8+i; B mirrored;
// D: col=l&15, row=(l>>4)*4+reg  [m89-verified, validated rounds 3-8].
// ---------------------------------------------------------------------------
template<int BM, int BN, int WM, int WN>
__global__ __launch_bounds__(256)
void qkv_mfma(const float* __restrict__ A, const float* __restrict__ W,
              const float* __restrict__ bias, _Float16* __restrict__ outh)
{
    constexpr int WTM = BM / WM;
    constexpr int WTN = BN / WN;
    constexpr int FM  = WTM / 16;
    constexpr int FN  = WTN / 16;
    const int row0 = blockIdx.x * BM;
    const int col0 = blockIdx.y * BN;
    const int t  = threadIdx.x;
    const int w  = t >> 6;
    const int l  = t & 63;
    const int wm = w / WN;
    const int wn = w % WN;

    __shared__ _Float16 Ah[BM * 128];
    __shared__ _Float16 Wh[BN * 128];

    {
        constexpr int AIT = BM * 32 / 256;          // float4s per thread
#pragma unroll
        for (int it = 0; it < AIT; ++it) {
            int idx = t + it * 256;
            int r = idx >> 5, k0 = (idx & 31) << 2;
            float4 v = *reinterpret_cast<const float4*>(A + (size_t)(row0 + r) * 128 + k0);
            union { _Float16 h[4]; uint2 u; } cv;
            cv.h[0] = (_Float16)v.x; cv.h[1] = (_Float16)v.y;
            cv.h[2] = (_Float16)v.z; cv.h[3] = (_Float16)v.w;
            *reinterpret_cast<uint2*>(&Ah[r * 128 + (k0 ^ ((r & 7) << 3))]) = cv.u;
        }
        constexpr int WIT = BN * 32 / 256;
#pragma unroll
        for (int it = 0; it < WIT; ++it) {
            int idx = t + it * 256;
            int r = idx >> 5, k0 = (idx & 31) << 2;
            float4 v = *reinterpret_cast<const float4*>(W + (size_t)(col0 + r) * 128 + k0);
            union { _Float16 h[4]; uint2 u; } cv;
            cv.h[0] = (_Float16)v.x; cv.h[1] = (_Float16)v.y;
            cv.h[2] = (_Float16)v.z; cv.h[3] = (_Float16)v.w;
            *reinterpret_cast<uint2*>(&Wh[r * 128 + (k0 ^ ((r & 7) << 3))]) = cv.u;
        }
    }
    __syncthreads();

    f32x4 acc[FM][FN];
#pragma unroll
    for (int mf = 0; mf < FM; ++mf)
#pragma unroll
        for (int nf = 0; nf < FN; ++nf) acc[mf][nf] = (f32x4){0.f, 0.f, 0.f, 0.f};

#pragma unroll
    for (int ks = 0; ks < 4; ++ks) {
        const int kb = ks * 32 + ((l >> 4) << 3);
        half8 a[FM], b[FN];
#pragma unroll
        for (int mf = 0; mf < FM; ++mf) {
            int m = wm * WTM + mf * 16 + (l & 15);
            a[mf] = *reinterpret_cast<const half8*>(&Ah[m * 128 + (kb ^ ((m & 7) << 3))]);
        }
#pragma unroll
        for (int nf = 0; nf < FN; ++nf) {
            int n = wn * WTN + nf * 16 + (l & 15);
            b[nf] = *reinterpret_cast<const half8*>(&Wh[n * 128 + (kb ^ ((n & 7) << 3))]);
        }
#pragma unroll
        for (int mf = 0; mf < FM; ++mf)
#pragma unroll
            for (int nf = 0; nf < FN; ++nf)
                acc[mf][nf] = __builtin_amdgcn_mfma_f32_16x16x32_f16(
                    a[mf], b[nf], acc[mf][nf], 0, 0, 0);
    }

#pragma unroll
    for (int mf = 0; mf < FM; ++mf) {
#pragma unroll
        for (int nf = 0; nf < FN; ++nf) {
#pragma unroll
            for (int r = 0; r < 4; ++r) {
                int row = row0 + wm * WTM + mf * 16 + ((l >> 4) << 2) + r;
                int col = col0 + wn * WTN + nf * 16 + (l & 15);
                float val = acc[mf][nf][r] + bias[col];
                int b_  = row / NPIX;
                int pix = row - b_ * NPIX;
                int which = col >> 7;          // 0=q 1=k 2=v
                outh[(size_t)which * QKV_STRIDE +
                     ((size_t)b_ * NPIX + pix) * 128 + (col & 127)] = (_Float16)val;
            }
        }
    }
}

// ---------------------------------------------------------------------------
// Fused neighborhood attention + output projection.
// Block = 8x4 pixel tile x ALL 4 heads x 4 lanes/pixel-head = 512 threads.
// Grid 98x4 = 392 blocks (3136 waves = 3.06/SIMD, same as the unfused natten).
// Dynamic LDS 76,160B (>64KB -> hipFuncSetAttribute opt-in; gfx950 has
// 160KB/WG):
//   phase 1: ksm[140][136], vsm[140][136] fp16 (K/V halo, all heads)
//   after QK barrier: att[32][136] overlays ksm (K dead)
//   after PV barrier: wsm[128][136] (proj W fp16) overlays vsm (V dead)
// Row stride 136 halves = 17 granules (odd) -> staging, QK/PV reads, att
// A-frags and Wp B-frags all cycle the 8 bank-quads evenly.
// QK/softmax/PV math is IDENTICAL to the validated R4-R8 kernel (fdot2 +
// quad DPP reduce; OOB neighbors zero -> logit=bias, kept in softmax).
// Proj: 8 waves x (16px x 32col) wave tiles, 8 MFMA each, fp32 out + bias.
// This deletes the standalone proj kernel: no 784x re-staging of W, no att
// global round-trip, one fewer launch gap.
// ---------------------------------------------------------------------------
__global__ __launch_bounds__(512, 4)
void natten_proj_k(const _Float16* __restrict__ qb, const _Float16* __restrict__ kb,
                   const _Float16* __restrict__ vb, const float* __restrict__ rpb,
                   const float* __restrict__ pw, const float* __restrict__ pb,
                   float* __restrict__ out)
{
    extern __shared__ _Float16 smem[];
    _Float16* ksm  = smem;               // [140][136]
    _Float16* vsm  = smem + HP * KVS;    // [140][136]
    _Float16* atts = smem;               // [32][136]  (overlays ksm after bar2)
    _Float16* wsm  = smem + HP * KVS;    // [128][136] (overlays vsm after bar3)

    const int tile = blockIdx.x;         // 0..97
    const int b    = blockIdx.y;         // 0..3
    const int ti = (tile / 14) * 8;
    const int tj = (tile % 14) * 4;
    const int t   = threadIdx.x;
    const int sub = t & 3;               // d-slice (8 halves) within head
    const int px  = (t >> 2) & 31;       // 0..31 local pixel
    const int pi  = px >> 2;             // 0..7
    const int pj  = px & 3;              // 0..3
    const int h   = t >> 7;              // 0..3 head (wave-uniform)

    const _Float16* kbase = kb + (size_t)b * NPIX * 128;
    const _Float16* vbase = vb + (size_t)b * NPIX * 128;

    // ---- stage K and V halo (all heads), 2240 granules over 512 threads ----
    for (int e = t; e < HP * 16; e += 512) {
        int p = e >> 4, g = e & 15;
        int wi = p / 10, wj = p - wi * 10;
        int gi = ti - 3 + wi, gj = tj - 3 + wj;
        bool ok = ((unsigned)gi < 56u) && ((unsigned)gj < 56u);
        size_t src = ((size_t)(gi * 56 + gj)) * 128 + g * 8;
        half8 kv = (half8){0,0,0,0,0,0,0,0};
        if (ok) kv = *reinterpret_cast<const half8*>(kbase + src);
        *reinterpret_cast<half8*>(&ksm[p * KVS + g * 8]) = kv;
        half8 vv = (half8){0,0,0,0,0,0,0,0};
        if (ok) vv = *reinterpret_cast<const half8*>(vbase + src);
        *reinterpret_cast<half8*>(&vsm[p * KVS + g * 8]) = vv;
    }

    // ---- q d-slice for this lane (in flight with staging) ----
    const int pix = (ti + pi) * 56 + (tj + pj);
    half8 qv = *reinterpret_cast<const half8*>(
        qb + ((size_t)b * NPIX + pix) * 128 + h * 32 + sub * 8);

    __syncthreads();                                   // bar1: K/V ready

    // ---- QK^T + bias ----
    const float* bias = rpb + h * 169;
    float logits[49];
    float m = -1e30f;
#pragma unroll
    for (int ki = 0; ki < 7; ++ki) {
#pragma unroll
        for (int kj = 0; kj < 7; ++kj) {
            int nb = (pi + ki) * 10 + (pj + kj);
            half8 kk = *reinterpret_cast<const half8*>(&ksm[nb * KVS + h * 32 + sub * 8]);
            float s = dot8h(qv, kk, 0.f);
            s = quad_reduce_sum(s);
            float lg = s * SCALE + bias[(ki + 3) * 13 + (kj + 3)];
            logits[ki * 7 + kj] = lg;
            m = fmaxf(m, lg);
        }
    }

    __syncthreads();                                   // bar2: K region free

    // ---- softmax (redundant per quad lane; cheap) ----
    float sum = 0.f;
#pragma unroll
    for (int n = 0; n < 49; ++n) {
        float e = __expf(logits[n] - m);
        logits[n] = e;
        sum += e;
    }
    float inv = 1.f / sum;

    // ---- P·V (fp32 accum) ----
    float o[8] = {0.f, 0.f, 0.f, 0.f, 0.f, 0.f, 0.f, 0.f};
#pragma unroll
    for (int ki = 0; ki < 7; ++ki) {
#pragma unroll
        for (int kj = 0; kj < 7; ++kj) {
            int nb = (pi + ki) * 10 + (pj + kj);
            half8 vv = *reinterpret_cast<const half8*>(&vsm[nb * KVS + h * 32 + sub * 8]);
            float wgt = logits[ki * 7 + kj];
#pragma unroll
            for (int i = 0; i < 8; ++i)
                o[i] += wgt * (float)vv[i];
        }
    }

    // ---- att -> LDS (K region), fp16 ----
    {
        half8 r;
#pragma unroll
        for (int i = 0; i < 8; ++i) r[i] = (_Float16)(o[i] * inv);
        *reinterpret_cast<half8*>(&atts[px * KVS + h * 32 + sub * 8]) = r;
    }

    __syncthreads();                                   // bar3: V reads + att writes done

    // ---- stage proj W (fp32 -> fp16) into V region: 2048 granules, 4 iters ----
    for (int e = t; e < 128 * 16; e += 512) {
        int r = e >> 4, g = e & 15;
        float4 w0 = *reinterpret_cast<const float4*>(pw + (size_t)r * 128 + g * 8);
        float4 w1 = *reinterpret_cast<const float4*>(pw + (size_t)r * 128 + g * 8 + 4);
        *reinterpret_cast<half8*>(&wsm[r * KVS + g * 8]) = cvt8(w0, w1);
    }

    __syncthreads();                                   // bar4: att + Wp ready

    // ---- projection: out[32px][128] = att @ Wp^T + pb ----
    const int w  = t >> 6;            // 0..7
    const int l  = t & 63;
    const int wm = w & 1;             // M tile (16 px)
    const int wn = w >> 1;            // N tile (32 cols)
    const int kb0 = (l >> 4) << 3;

    f32x4 acc0 = (f32x4){0.f, 0.f, 0.f, 0.f};
    f32x4 acc1 = (f32x4){0.f, 0.f, 0.f, 0.f};
#pragma unroll
    for (int ks = 0; ks < 4; ++ks) {
        const int kb = ks * 32 + kb0;
        half8 a  = *reinterpret_cast<const half8*>(&atts[(wm * 16 + (l & 15)) * KVS + kb]);
        half8 b0 = *reinterpret_cast<const half8*>(&wsm[(wn * 32 + (l & 15)) * KVS + kb]);
        half8 b1 = *reinterpret_cast<const half8*>(&wsm[(wn * 32 + 16 + (l & 15)) * KVS + kb]);
        acc0 = __builtin_amdgcn_mfma_f32_16x16x32_f16(a, b0, acc0, 0, 0, 0);
        acc1 = __builtin_amdgcn_mfma_f32_16x16x32_f16(a, b1, acc1, 0, 0, 0);
    }

#pragma unroll
    for (int r = 0; r < 4; ++r) {
        int prow = wm * 16 + ((l >> 4) << 2) + r;          // local pixel 0..31
        int gpix = (ti + (prow >> 2)) * 56 + tj + (prow & 3);
        float* dst = out + ((size_t)b * NPIX + gpix) * 128;
        int c0 = wn * 32 + (l & 15);
        dst[c0]      = acc0[r] + pb[c0];
        dst[c0 + 16] = acc1[r] + pb[c0 + 16];
    }
}

// ---------------------------------------------------------------------------
extern "C" void kernel_launch(void* const* d_in, const int* in_sizes, int n_in,
                              void* d_out, int out_size, void* d_ws, size_t ws_size,
                              hipStream_t stream)
{
    const float* x      = (const float*)d_in[0];
    const float* qkv_w  = (const float*)d_in[1];
    const float* qkv_b  = (const float*)d_in[2];
    const float* rpb    = (const float*)d_in[3];
    const float* proj_w = (const float*)d_in[4];
    const float* proj_b = (const float*)d_in[5];
    float* out = (float*)d_out;

    // ws layout (fp16): q | k | v  (3.2 MB each), each [b][pix][128]
    _Float16* qbuf = (_Float16*)d_ws;
    _Float16* kbuf = qbuf + (size_t)QKV_STRIDE;
    _Float16* vbuf = kbuf + (size_t)QKV_STRIDE;

    // opt-in to 76,160B dynamic LDS (>64KB default cap); idempotent host-side
    // call, not a stream op -> graph-capture safe
    hipFuncSetAttribute((const void*)natten_proj_k,
                        hipFuncAttributeMaxDynamicSharedMemorySize,
                        2 * HP * KVS * (int)sizeof(_Float16));

    // 1) QKV projection: [12544,128] @ [384,128]^T -> fp16 q/k/v (head-contig)
    qkv_mfma<64, 128, 2, 2><<<dim3(196, 3), dim3(256), 0, stream>>>(
        x, qkv_w, qkv_b, qbuf);

    // 2) fused neighborhood attention + output projection
    natten_proj_k<<<dim3(98, 4), dim3(512),
                    2 * HP * KVS * sizeof(_Float16), stream>>>(
        qbuf, kbuf, vbuf, rpb, proj_w, proj_b, out);
}

// Round 10
// 33.629 us; speedup vs baseline: 1.5487x; 1.0277x over previous
//
#include <hip/hip_runtime.h>

#define NPIX   3136        // 56*56
#define MROWS  12544       // 4*3136
#define QKV_STRIDE 1605632 // MROWS*128 halves per q/k/v buffer
#define SCALE  0.17677669529663687f  // 32^-0.5
#define KVS    136         // LDS row stride (halves): 17 granules, odd -> even bank spread
#define HP     140         // halo pixels per fused block (14 x 10)

typedef __attribute__((ext_vector_type(8))) _Float16 half8;
typedef __attribute__((ext_vector_type(2))) _Float16 v2h;
typedef __attribute__((ext_vector_type(4))) float    f32x4;

#if defined(__has_builtin)
#if __has_builtin(__builtin_amdgcn_fdot2)
#define HAS_FDOT2 1
#endif
#endif

// sum across each aligned quad of 4 lanes via DPP quad_perm
__device__ __forceinline__ float quad_reduce_sum(float x) {
    x += __int_as_float(__builtin_amdgcn_mov_dpp(__float_as_int(x), 0xB1, 0xF, 0xF, true));
    x += __int_as_float(__builtin_amdgcn_mov_dpp(__float_as_int(x), 0x4E, 0xF, 0xF, true));
    return x;
}

// 8-wide fp16 dot with fp32 accumulate (v_dot2_f32_f16 x4)
__device__ __forceinline__ float dot8h(half8 a, half8 b, float acc) {
#ifdef HAS_FDOT2
    union { half8 v; v2h p[4]; } ua, ub;
    ua.v = a; ub.v = b;
    acc = __builtin_amdgcn_fdot2(ua.p[0], ub.p[0], acc, false);
    acc = __builtin_amdgcn_fdot2(ua.p[1], ub.p[1], acc, false);
    acc = __builtin_amdgcn_fdot2(ua.p[2], ub.p[2], acc, false);
    acc = __builtin_amdgcn_fdot2(ua.p[3], ub.p[3], acc, false);
#else
#pragma unroll
    for (int i = 0; i < 8; ++i) acc += (float)a[i] * (float)b[i];
#endif
    return acc;
}

// ---------------------------------------------------------------------------
// QKV GEMM — R4-validated structure/config (pinned since R8). Also performs
// the ONE-TIME proj_w fp32->fp16 conversion (16 of 588 blocks, 1 float4 per
// thread) so the fused kernel never touches fp32 W — deletes 392x re-convert.
// Fragment maps (16x16x32): A: m=l&15, k=(l>>4)*8+i; B mirrored;
// D: col=l&15, row=(l>>4)*4+reg  [m89-verified, validated rounds 3-9].
// Scatter: head-contiguous fp16 [which][b][pix][128].
// ---------------------------------------------------------------------------
template<int BM, int BN, int WM, int WN>
__global__ __launch_bounds__(256)
void qkv_mfma(const float* __restrict__ A, const float* __restrict__ W,
              const float* __restrict__ bias, _Float16* __restrict__ outh,
              const float* __restrict__ pw, _Float16* __restrict__ pwh)
{
    constexpr int WTM = BM / WM;
    constexpr int WTN = BN / WN;
    constexpr int FM  = WTM / 16;
    constexpr int FN  = WTN / 16;
    const int row0 = blockIdx.x * BM;
    const int col0 = blockIdx.y * BN;
    const int t  = threadIdx.x;
    const int w  = t >> 6;
    const int l  = t & 63;
    const int wm = w / WN;
    const int wn = w % WN;

    // folded one-time proj_w conversion (128x128 = 4096 float4s)
    if (blockIdx.y == 0 && blockIdx.x < 16) {
        int idx = blockIdx.x * 256 + t;
        float4 v = *reinterpret_cast<const float4*>(pw + (size_t)idx * 4);
        union { _Float16 h[4]; uint2 u; } cv;
        cv.h[0] = (_Float16)v.x; cv.h[1] = (_Float16)v.y;
        cv.h[2] = (_Float16)v.z; cv.h[3] = (_Float16)v.w;
        *reinterpret_cast<uint2*>(pwh + (size_t)idx * 4) = cv.u;
    }

    __shared__ _Float16 Ah[BM * 128];
    __shared__ _Float16 Wh[BN * 128];

    {
        constexpr int AIT = BM * 32 / 256;          // float4s per thread
#pragma unroll
        for (int it = 0; it < AIT; ++it) {
            int idx = t + it * 256;
            int r = idx >> 5, k0 = (idx & 31) << 2;
            float4 v = *reinterpret_cast<const float4*>(A + (size_t)(row0 + r) * 128 + k0);
            union { _Float16 h[4]; uint2 u; } cv;
            cv.h[0] = (_Float16)v.x; cv.h[1] = (_Float16)v.y;
            cv.h[2] = (_Float16)v.z; cv.h[3] = (_Float16)v.w;
            *reinterpret_cast<uint2*>(&Ah[r * 128 + (k0 ^ ((r & 7) << 3))]) = cv.u;
        }
        constexpr int WIT = BN * 32 / 256;
#pragma unroll
        for (int it = 0; it < WIT; ++it) {
            int idx = t + it * 256;
            int r = idx >> 5, k0 = (idx & 31) << 2;
            float4 v = *reinterpret_cast<const float4*>(W + (size_t)(col0 + r) * 128 + k0);
            union { _Float16 h[4]; uint2 u; } cv;
            cv.h[0] = (_Float16)v.x; cv.h[1] = (_Float16)v.y;
            cv.h[2] = (_Float16)v.z; cv.h[3] = (_Float16)v.w;
            *reinterpret_cast<uint2*>(&Wh[r * 128 + (k0 ^ ((r & 7) << 3))]) = cv.u;
        }
    }
    __syncthreads();

    f32x4 acc[FM][FN];
#pragma unroll
    for (int mf = 0; mf < FM; ++mf)
#pragma unroll
        for (int nf = 0; nf < FN; ++nf) acc[mf][nf] = (f32x4){0.f, 0.f, 0.f, 0.f};

#pragma unroll
    for (int ks = 0; ks < 4; ++ks) {
        const int kb = ks * 32 + ((l >> 4) << 3);
        half8 a[FM], b[FN];
#pragma unroll
        for (int mf = 0; mf < FM; ++mf) {
            int m = wm * WTM + mf * 16 + (l & 15);
            a[mf] = *reinterpret_cast<const half8*>(&Ah[m * 128 + (kb ^ ((m & 7) << 3))]);
        }
#pragma unroll
        for (int nf = 0; nf < FN; ++nf) {
            int n = wn * WTN + nf * 16 + (l & 15);
            b[nf] = *reinterpret_cast<const half8*>(&Wh[n * 128 + (kb ^ ((n & 7) << 3))]);
        }
#pragma unroll
        for (int mf = 0; mf < FM; ++mf)
#pragma unroll
            for (int nf = 0; nf < FN; ++nf)
                acc[mf][nf] = __builtin_amdgcn_mfma_f32_16x16x32_f16(
                    a[mf], b[nf], acc[mf][nf], 0, 0, 0);
    }

#pragma unroll
    for (int mf = 0; mf < FM; ++mf) {
#pragma unroll
        for (int nf = 0; nf < FN; ++nf) {
#pragma unroll
            for (int r = 0; r < 4; ++r) {
                int row = row0 + wm * WTM + mf * 16 + ((l >> 4) << 2) + r;
                int col = col0 + wn * WTN + nf * 16 + (l & 15);
                float val = acc[mf][nf][r] + bias[col];
                int b_  = row / NPIX;
                int pix = row - b_ * NPIX;
                int which = col >> 7;          // 0=q 1=k 2=v
                outh[(size_t)which * QKV_STRIDE +
                     ((size_t)b_ * NPIX + pix) * 128 + (col & 127)] = (_Float16)val;
            }
        }
    }
}

// ---------------------------------------------------------------------------
// Fused neighborhood attention + output projection (R9 structure, leaner tail).
// Block = 8x4 pixel tile x 4 heads x 4 lanes = 512 threads; grid 98x4 = 392.
// Dynamic LDS 76,160B: ksm[140][136] + vsm[140][136] fp16; atts[32][136]
// overlays ksm after bar2. R10 changes vs R9:
//  - proj W comes from the PRE-CONVERTED fp16 copy, loaded straight into 8
//    half8 REGISTERS per lane, issued right after PV so L2 latency hides
//    under the att-write + bar3 sync (T14 issue-early/consume-late).
//  - wsm LDS staging, its ds traffic, the 2048 cvts, and bar4 are deleted
//    (3 barriers total).
//  - q-load hoisted above K/V staging for explicit early issue.
// QK/softmax/PV math identical to the R4-R9 validated kernel. OOB neighbors
// zero -> logit = bias only, kept in softmax (reference zero-pad semantics).
// ---------------------------------------------------------------------------
__global__ __launch_bounds__(512, 4)
void natten_proj_k(const _Float16* __restrict__ qb, const _Float16* __restrict__ kb,
                   const _Float16* __restrict__ vb, const float* __restrict__ rpb,
                   const _Float16* __restrict__ pwh, const float* __restrict__ pb,
                   float* __restrict__ out)
{
    extern __shared__ _Float16 smem[];
    _Float16* ksm  = smem;               // [140][136]
    _Float16* vsm  = smem + HP * KVS;    // [140][136]
    _Float16* atts = smem;               // [32][136]  (overlays ksm after bar2)

    const int tile = blockIdx.x;         // 0..97
    const int b    = blockIdx.y;         // 0..3
    const int ti = (tile / 14) * 8;
    const int tj = (tile % 14) * 4;
    const int t   = threadIdx.x;
    const int sub = t & 3;               // d-slice (8 halves) within head
    const int px  = (t >> 2) & 31;       // 0..31 local pixel
    const int pi  = px >> 2;             // 0..7
    const int pj  = px & 3;              // 0..3
    const int h   = t >> 7;              // 0..3 head (wave-uniform)

    const _Float16* kbase = kb + (size_t)b * NPIX * 128;
    const _Float16* vbase = vb + (size_t)b * NPIX * 128;

    // ---- q d-slice for this lane (issued first) ----
    const int pix = (ti + pi) * 56 + (tj + pj);
    half8 qv = *reinterpret_cast<const half8*>(
        qb + ((size_t)b * NPIX + pix) * 128 + h * 32 + sub * 8);

    // ---- stage K and V halo (all heads), 2240 granules over 512 threads ----
    for (int e = t; e < HP * 16; e += 512) {
        int p = e >> 4, g = e & 15;
        int wi = p / 10, wj = p - wi * 10;
        int gi = ti - 3 + wi, gj = tj - 3 + wj;
        bool ok = ((unsigned)gi < 56u) && ((unsigned)gj < 56u);
        size_t src = ((size_t)(gi * 56 + gj)) * 128 + g * 8;
        half8 kv = (half8){0,0,0,0,0,0,0,0};
        if (ok) kv = *reinterpret_cast<const half8*>(kbase + src);
        *reinterpret_cast<half8*>(&ksm[p * KVS + g * 8]) = kv;
        half8 vv = (half8){0,0,0,0,0,0,0,0};
        if (ok) vv = *reinterpret_cast<const half8*>(vbase + src);
        *reinterpret_cast<half8*>(&vsm[p * KVS + g * 8]) = vv;
    }

    __syncthreads();                                   // bar1: K/V ready

    // ---- QK^T + bias ----
    const float* bias = rpb + h * 169;
    float logits[49];
    float m = -1e30f;
#pragma unroll
    for (int ki = 0; ki < 7; ++ki) {
#pragma unroll
        for (int kj = 0; kj < 7; ++kj) {
            int nb = (pi + ki) * 10 + (pj + kj);
            half8 kk = *reinterpret_cast<const half8*>(&ksm[nb * KVS + h * 32 + sub * 8]);
            float s = dot8h(qv, kk, 0.f);
            s = quad_reduce_sum(s);
            float lg = s * SCALE + bias[(ki + 3) * 13 + (kj + 3)];
            logits[ki * 7 + kj] = lg;
            m = fmaxf(m, lg);
        }
    }

    __syncthreads();                                   // bar2: K region free

    // ---- softmax (redundant per quad lane; cheap) ----
    float sum = 0.f;
#pragma unroll
    for (int n = 0; n < 49; ++n) {
        float e = __expf(logits[n] - m);
        logits[n] = e;
        sum += e;
    }
    float inv = 1.f / sum;

    // ---- P·V (fp32 accum) ----
    float o[8] = {0.f, 0.f, 0.f, 0.f, 0.f, 0.f, 0.f, 0.f};
#pragma unroll
    for (int ki = 0; ki < 7; ++ki) {
#pragma unroll
        for (int kj = 0; kj < 7; ++kj) {
            int nb = (pi + ki) * 10 + (pj + kj);
            half8 vv = *reinterpret_cast<const half8*>(&vsm[nb * KVS + h * 32 + sub * 8]);
            float wgt = logits[ki * 7 + kj];
#pragma unroll
            for (int i = 0; i < 8; ++i)
                o[i] += wgt * (float)vv[i];
        }
    }

    // ---- proj W B-fragments -> registers (issued now; consumed after bar3,
    //      latency hidden under att-write + barrier sync) ----
    const int l   = t & 63;
    const int wv  = t >> 6;           // 0..7
    const int wm  = wv & 1;           // M tile (16 px)
    const int wn  = wv >> 1;          // N tile (32 cols)
    const int kb0 = (l >> 4) << 3;
    half8 wreg[8];
#pragma unroll
    for (int ks = 0; ks < 4; ++ks) {
        const _Float16* wp = pwh + (size_t)(wn * 32 + (l & 15)) * 128 + ks * 32 + kb0;
        wreg[ks]     = *reinterpret_cast<const half8*>(wp);
        wreg[4 + ks] = *reinterpret_cast<const half8*>(wp + 16 * 128);
    }

    // ---- att -> LDS (K region), fp16 ----
    {
        half8 r;
#pragma unroll
        for (int i = 0; i < 8; ++i) r[i] = (_Float16)(o[i] * inv);
        *reinterpret_cast<half8*>(&atts[px * KVS + h * 32 + sub * 8]) = r;
    }

    __syncthreads();                                   // bar3: att ready

    // ---- projection: out[32px][128] = att @ Wp^T + pb (B from registers) ----
    f32x4 acc0 = (f32x4){0.f, 0.f, 0.f, 0.f};
    f32x4 acc1 = (f32x4){0.f, 0.f, 0.f, 0.f};
#pragma unroll
    for (int ks = 0; ks < 4; ++ks) {
        const int kb = ks * 32 + kb0;
        half8 a = *reinterpret_cast<const half8*>(&atts[(wm * 16 + (l & 15)) * KVS + kb]);
        acc0 = __builtin_amdgcn_mfma_f32_16x16x32_f16(a, wreg[ks],     acc0, 0, 0, 0);
        acc1 = __builtin_amdgcn_mfma_f32_16x16x32_f16(a, wreg[4 + ks], acc1, 0, 0, 0);
    }

#pragma unroll
    for (int r = 0; r < 4; ++r) {
        int prow = wm * 16 + ((l >> 4) << 2) + r;          // local pixel 0..31
        int gpix = (ti + (prow >> 2)) * 56 + tj + (prow & 3);
        float* dst = out + ((size_t)b * NPIX + gpix) * 128;
        int c0 = wn * 32 + (l & 15);
        dst[c0]      = acc0[r] + pb[c0];
        dst[c0 + 16] = acc1[r] + pb[c0 + 16];
    }
}

// ---------------------------------------------------------------------------
extern "C" void kernel_launch(void* const* d_in, const int* in_sizes, int n_in,
                              void* d_out, int out_size, void* d_ws, size_t ws_size,
                              hipStream_t stream)
{
    const float* x      = (const float*)d_in[0];
    const float* qkv_w  = (const float*)d_in[1];
    const float* qkv_b  = (const float*)d_in[2];
    const float* rpb    = (const float*)d_in[3];
    const float* proj_w = (const float*)d_in[4];
    const float* proj_b = (const float*)d_in[5];
    float* out = (float*)d_out;

    // ws layout (fp16): q | k | v (3.2 MB each, [b][pix][128]) | proj_w fp16
    _Float16* qbuf = (_Float16*)d_ws;
    _Float16* kbuf = qbuf + (size_t)QKV_STRIDE;
    _Float16* vbuf = kbuf + (size_t)QKV_STRIDE;
    _Float16* pwh  = vbuf + (size_t)QKV_STRIDE;   // 128*128 halves = 32 KB

    // opt-in to 76,160B dynamic LDS (>64KB default cap); host-side, graph-safe
    hipFuncSetAttribute((const void*)natten_proj_k,
                        hipFuncAttributeMaxDynamicSharedMemorySize,
                        2 * HP * KVS * (int)sizeof(_Float16));

    // 1) QKV projection (+ folded proj_w fp16 conversion)
    qkv_mfma<64, 128, 2, 2><<<dim3(196, 3), dim3(256), 0, stream>>>(
        x, qkv_w, qkv_b, qbuf, proj_w, pwh);

    // 2) fused neighborhood attention + output projection
    natten_proj_k<<<dim3(98, 4), dim3(512),
                    2 * HP * KVS * sizeof(_Float16), stream>>>(
        qbuf, kbuf, vbuf, rpb, pwh, proj_b, out);
}

// Round 11
// 30.408 us; speedup vs baseline: 1.7127x; 1.1059x over previous
//
#include <hip/hip_runtime.h>

#define NPIX   3136        // 56*56
#define MROWS  12544       // 4*3136
#define QKV_STRIDE 1605632 // MROWS*128 halves per q/k/v buffer
#define SCALE  0.17677669529663687f  // 32^-0.5
#define KVS    136         // LDS row stride (halves): 17 granules, odd -> even bank spread
#define HP     140         // halo pixels per fused block (14 x 10)

typedef __attribute__((ext_vector_type(8))) _Float16 half8;
typedef __attribute__((ext_vector_type(2))) _Float16 v2h;
typedef __attribute__((ext_vector_type(4))) float    f32x4;

#if defined(__has_builtin)
#if __has_builtin(__builtin_amdgcn_fdot2)
#define HAS_FDOT2 1
#endif
#endif

// sum across each aligned quad of 4 lanes via DPP quad_perm
__device__ __forceinline__ float quad_reduce_sum(float x) {
    x += __int_as_float(__builtin_amdgcn_mov_dpp(__float_as_int(x), 0xB1, 0xF, 0xF, true));
    x += __int_as_float(__builtin_amdgcn_mov_dpp(__float_as_int(x), 0x4E, 0xF, 0xF, true));
    return x;
}

// 8-wide fp16 dot with fp32 accumulate (v_dot2_f32_f16 x4)
__device__ __forceinline__ float dot8h(half8 a, half8 b, float acc) {
#ifdef HAS_FDOT2
    union { half8 v; v2h p[4]; } ua, ub;
    ua.v = a; ub.v = b;
    acc = __builtin_amdgcn_fdot2(ua.p[0], ub.p[0], acc, false);
    acc = __builtin_amdgcn_fdot2(ua.p[1], ub.p[1], acc, false);
    acc = __builtin_amdgcn_fdot2(ua.p[2], ub.p[2], acc, false);
    acc = __builtin_amdgcn_fdot2(ua.p[3], ub.p[3], acc, false);
#else
#pragma unroll
    for (int i = 0; i < 8; ++i) acc += (float)a[i] * (float)b[i];
#endif
    return acc;
}

// ---------------------------------------------------------------------------
// QKV GEMM — R4 tile config (pinned), R11: 2-chunk K-pipelined staging.
// K split into two 64-wide chunks occupying DISJOINT k-columns of the same
// LDS buffer (no extra region, no extra hazard): chunk-1 global loads are
// issued immediately after bar1 so their ~500cy latency hides under chunk-0's
// 16 MFMAs (the kernel was a single stage->barrier->compute chain with only
// 2.3 blocks/CU to cover it). Math/accumulation order unchanged.
// Also performs the one-time proj_w fp32->fp16 conversion (16 of 588 blocks).
// Fragment maps (16x16x32): A: m=l&15, k=(l>>4)*8+i; B mirrored;
// D: col=l&15, row=(l>>4)*4+reg  [m89-verified, validated rounds 3-10].
// Scatter: head-contiguous fp16 [which][b][pix][128].
// ---------------------------------------------------------------------------
template<int BM, int BN, int WM, int WN>
__global__ __launch_bounds__(256)
void qkv_mfma(const float* __restrict__ A, const float* __restrict__ W,
              const float* __restrict__ bias, _Float16* __restrict__ outh,
              const float* __restrict__ pw, _Float16* __restrict__ pwh)
{
    constexpr int WTM = BM / WM;
    constexpr int WTN = BN / WN;
    constexpr int FM  = WTM / 16;
    constexpr int FN  = WTN / 16;
    constexpr int AIT = BM * 16 / 256;   // float4s per thread per 64-K chunk
    constexpr int WIT = BN * 16 / 256;
    const int row0 = blockIdx.x * BM;
    const int col0 = blockIdx.y * BN;
    const int t  = threadIdx.x;
    const int w  = t >> 6;
    const int l  = t & 63;
    const int wm = w / WN;
    const int wn = w % WN;

    // folded one-time proj_w conversion (128x128 = 4096 float4s)
    if (blockIdx.y == 0 && blockIdx.x < 16) {
        int idx = blockIdx.x * 256 + t;
        float4 v = *reinterpret_cast<const float4*>(pw + (size_t)idx * 4);
        union { _Float16 h[4]; uint2 u; } cv;
        cv.h[0] = (_Float16)v.x; cv.h[1] = (_Float16)v.y;
        cv.h[2] = (_Float16)v.z; cv.h[3] = (_Float16)v.w;
        *reinterpret_cast<uint2*>(pwh + (size_t)idx * 4) = cv.u;
    }

    __shared__ _Float16 Ah[BM * 128];
    __shared__ _Float16 Wh[BN * 128];

    float4 pa[AIT], pwr[WIT];

    // ---- load chunk 0 (k 0..63) into registers ----
#pragma unroll
    for (int it = 0; it < AIT; ++it) {
        int idx = t + it * 256;
        int r = idx >> 4, k0 = (idx & 15) << 2;
        pa[it] = *reinterpret_cast<const float4*>(A + (size_t)(row0 + r) * 128 + k0);
    }
#pragma unroll
    for (int it = 0; it < WIT; ++it) {
        int idx = t + it * 256;
        int r = idx >> 4, k0 = (idx & 15) << 2;
        pwr[it] = *reinterpret_cast<const float4*>(W + (size_t)(col0 + r) * 128 + k0);
    }
    // ---- write chunk 0 to LDS (cvt fp16, swizzled) ----
#pragma unroll
    for (int it = 0; it < AIT; ++it) {
        int idx = t + it * 256;
        int r = idx >> 4, k0 = (idx & 15) << 2;
        union { _Float16 h[4]; uint2 u; } cv;
        cv.h[0] = (_Float16)pa[it].x; cv.h[1] = (_Float16)pa[it].y;
        cv.h[2] = (_Float16)pa[it].z; cv.h[3] = (_Float16)pa[it].w;
        *reinterpret_cast<uint2*>(&Ah[r * 128 + (k0 ^ ((r & 7) << 3))]) = cv.u;
    }
#pragma unroll
    for (int it = 0; it < WIT; ++it) {
        int idx = t + it * 256;
        int r = idx >> 4, k0 = (idx & 15) << 2;
        union { _Float16 h[4]; uint2 u; } cv;
        cv.h[0] = (_Float16)pwr[it].x; cv.h[1] = (_Float16)pwr[it].y;
        cv.h[2] = (_Float16)pwr[it].z; cv.h[3] = (_Float16)pwr[it].w;
        *reinterpret_cast<uint2*>(&Wh[r * 128 + (k0 ^ ((r & 7) << 3))]) = cv.u;
    }
    __syncthreads();                     // bar1: chunk 0 ready

    // ---- issue chunk 1 loads (k 64..127) — fly under chunk-0 MFMAs ----
#pragma unroll
    for (int it = 0; it < AIT; ++it) {
        int idx = t + it * 256;
        int r = idx >> 4, k0 = 64 + ((idx & 15) << 2);
        pa[it] = *reinterpret_cast<const float4*>(A + (size_t)(row0 + r) * 128 + k0);
    }
#pragma unroll
    for (int it = 0; it < WIT; ++it) {
        int idx = t + it * 256;
        int r = idx >> 4, k0 = 64 + ((idx & 15) << 2);
        pwr[it] = *reinterpret_cast<const float4*>(W + (size_t)(col0 + r) * 128 + k0);
    }

    f32x4 acc[FM][FN];
#pragma unroll
    for (int mf = 0; mf < FM; ++mf)
#pragma unroll
        for (int nf = 0; nf < FN; ++nf) acc[mf][nf] = (f32x4){0.f, 0.f, 0.f, 0.f};

    // ---- compute chunk 0 (ks 0,1) ----
#pragma unroll
    for (int ks = 0; ks < 2; ++ks) {
        const int kb = ks * 32 + ((l >> 4) << 3);
        half8 a[FM], b[FN];
#pragma unroll
        for (int mf = 0; mf < FM; ++mf) {
            int m = wm * WTM + mf * 16 + (l & 15);
            a[mf] = *reinterpret_cast<const half8*>(&Ah[m * 128 + (kb ^ ((m & 7) << 3))]);
        }
#pragma unroll
        for (int nf = 0; nf < FN; ++nf) {
            int n = wn * WTN + nf * 16 + (l & 15);
            b[nf] = *reinterpret_cast<const half8*>(&Wh[n * 128 + (kb ^ ((n & 7) << 3))]);
        }
#pragma unroll
        for (int mf = 0; mf < FM; ++mf)
#pragma unroll
            for (int nf = 0; nf < FN; ++nf)
                acc[mf][nf] = __builtin_amdgcn_mfma_f32_16x16x32_f16(
                    a[mf], b[nf], acc[mf][nf], 0, 0, 0);
    }

    // ---- write chunk 1 to LDS (disjoint k-columns; no hazard with c0 reads) ----
#pragma unroll
    for (int it = 0; it < AIT; ++it) {
        int idx = t + it * 256;
        int r = idx >> 4, k0 = 64 + ((idx & 15) << 2);
        union { _Float16 h[4]; uint2 u; } cv;
        cv.h[0] = (_Float16)pa[it].x; cv.h[1] = (_Float16)pa[it].y;
        cv.h[2] = (_Float16)pa[it].z; cv.h[3] = (_Float16)pa[it].w;
        *reinterpret_cast<uint2*>(&Ah[r * 128 + (k0 ^ ((r & 7) << 3))]) = cv.u;
    }
#pragma unroll
    for (int it = 0; it < WIT; ++it) {
        int idx = t + it * 256;
        int r = idx >> 4, k0 = 64 + ((idx & 15) << 2);
        union { _Float16 h[4]; uint2 u; } cv;
        cv.h[0] = (_Float16)pwr[it].x; cv.h[1] = (_Float16)pwr[it].y;
        cv.h[2] = (_Float16)pwr[it].z; cv.h[3] = (_Float16)pwr[it].w;
        *reinterpret_cast<uint2*>(&Wh[r * 128 + (k0 ^ ((r & 7) << 3))]) = cv.u;
    }
    __syncthreads();                     // bar2: chunk 1 ready

    // ---- compute chunk 1 (ks 2,3) ----
#pragma unroll
    for (int ks = 2; ks < 4; ++ks) {
        const int kb = ks * 32 + ((l >> 4) << 3);
        half8 a[FM], b[FN];
#pragma unroll
        for (int mf = 0; mf < FM; ++mf) {
            int m = wm * WTM + mf * 16 + (l & 15);
            a[mf] = *reinterpret_cast<const half8*>(&Ah[m * 128 + (kb ^ ((m & 7) << 3))]);
        }
#pragma unroll
        for (int nf = 0; nf < FN; ++nf) {
            int n = wn * WTN + nf * 16 + (l & 15);
            b[nf] = *reinterpret_cast<const half8*>(&Wh[n * 128 + (kb ^ ((n & 7) << 3))]);
        }
#pragma unroll
        for (int mf = 0; mf < FM; ++mf)
#pragma unroll
            for (int nf = 0; nf < FN; ++nf)
                acc[mf][nf] = __builtin_amdgcn_mfma_f32_16x16x32_f16(
                    a[mf], b[nf], acc[mf][nf], 0, 0, 0);
    }

    // ---- epilogue ----
#pragma unroll
    for (int mf = 0; mf < FM; ++mf) {
#pragma unroll
        for (int nf = 0; nf < FN; ++nf) {
#pragma unroll
            for (int r = 0; r < 4; ++r) {
                int row = row0 + wm * WTM + mf * 16 + ((l >> 4) << 2) + r;
                int col = col0 + wn * WTN + nf * 16 + (l & 15);
                float val = acc[mf][nf][r] + bias[col];
                int b_  = row / NPIX;
                int pix = row - b_ * NPIX;
                int which = col >> 7;          // 0=q 1=k 2=v
                outh[(size_t)which * QKV_STRIDE +
                     ((size_t)b_ * NPIX + pix) * 128 + (col & 127)] = (_Float16)val;
            }
        }
    }
}

// ---------------------------------------------------------------------------
// Fused neighborhood attention + output projection (R10 structure).
// R11 change: bijective XCD-aware block swizzle (T1). Grid is flat 392 = 8*49
// exactly; HW round-robins linear block id over the 8 XCDs, so
// rank = (flat&7)*49 + (flat>>3) gives each XCD 49 CONSECUTIVE tiles —
// neighboring 4-px tiles share 60% of their K/V halo, which now hits the
// same XCD's L2 instead of missing to L3.
// Everything else identical to R10 (validated).
// ---------------------------------------------------------------------------
__global__ __launch_bounds__(512, 4)
void natten_proj_k(const _Float16* __restrict__ qb, const _Float16* __restrict__ kb,
                   const _Float16* __restrict__ vb, const float* __restrict__ rpb,
                   const _Float16* __restrict__ pwh, const float* __restrict__ pb,
                   float* __restrict__ out)
{
    extern __shared__ _Float16 smem[];
    _Float16* ksm  = smem;               // [140][136]
    _Float16* vsm  = smem + HP * KVS;    // [140][136]
    _Float16* atts = smem;               // [32][136]  (overlays ksm after bar2)

    // bijective XCD swizzle: XCD c (= flat%8) gets ranks [49c, 49c+49)
    const int flat = blockIdx.x;         // 0..391
    const int rank = (flat & 7) * 49 + (flat >> 3);
    const int tile = rank % 98;
    const int b    = rank / 98;          // 0..3
    const int ti = (tile / 14) * 8;
    const int tj = (tile % 14) * 4;
    const int t   = threadIdx.x;
    const int sub = t & 3;               // d-slice (8 halves) within head
    const int px  = (t >> 2) & 31;       // 0..31 local pixel
    const int pi  = px >> 2;             // 0..7
    const int pj  = px & 3;              // 0..3
    const int h   = t >> 7;              // 0..3 head (wave-uniform)

    const _Float16* kbase = kb + (size_t)b * NPIX * 128;
    const _Float16* vbase = vb + (size_t)b * NPIX * 128;

    // ---- q d-slice for this lane (issued first) ----
    const int pix = (ti + pi) * 56 + (tj + pj);
    half8 qv = *reinterpret_cast<const half8*>(
        qb + ((size_t)b * NPIX + pix) * 128 + h * 32 + sub * 8);

    // ---- stage K and V halo (all heads), 2240 granules over 512 threads ----
    for (int e = t; e < HP * 16; e += 512) {
        int p = e >> 4, g = e & 15;
        int wi = p / 10, wj = p - wi * 10;
        int gi = ti - 3 + wi, gj = tj - 3 + wj;
        bool ok = ((unsigned)gi < 56u) && ((unsigned)gj < 56u);
        size_t src = ((size_t)(gi * 56 + gj)) * 128 + g * 8;
        half8 kv = (half8){0,0,0,0,0,0,0,0};
        if (ok) kv = *reinterpret_cast<const half8*>(kbase + src);
        *reinterpret_cast<half8*>(&ksm[p * KVS + g * 8]) = kv;
        half8 vv = (half8){0,0,0,0,0,0,0,0};
        if (ok) vv = *reinterpret_cast<const half8*>(vbase + src);
        *reinterpret_cast<half8*>(&vsm[p * KVS + g * 8]) = vv;
    }

    __syncthreads();                                   // bar1: K/V ready

    // ---- QK^T + bias ----
    const float* bias = rpb + h * 169;
    float logits[49];
    float m = -1e30f;
#pragma unroll
    for (int ki = 0; ki < 7; ++ki) {
#pragma unroll
        for (int kj = 0; kj < 7; ++kj) {
            int nb = (pi + ki) * 10 + (pj + kj);
            half8 kk = *reinterpret_cast<const half8*>(&ksm[nb * KVS + h * 32 + sub * 8]);
            float s = dot8h(qv, kk, 0.f);
            s = quad_reduce_sum(s);
            float lg = s * SCALE + bias[(ki + 3) * 13 + (kj + 3)];
            logits[ki * 7 + kj] = lg;
            m = fmaxf(m, lg);
        }
    }

    __syncthreads();                                   // bar2: K region free

    // ---- softmax (redundant per quad lane; cheap) ----
    float sum = 0.f;
#pragma unroll
    for (int n = 0; n < 49; ++n) {
        float e = __expf(logits[n] - m);
        logits[n] = e;
        sum += e;
    }
    float inv = 1.f / sum;

    // ---- P·V (fp32 accum) ----
    float o[8] = {0.f, 0.f, 0.f, 0.f, 0.f, 0.f, 0.f, 0.f};
#pragma unroll
    for (int ki = 0; ki < 7; ++ki) {
#pragma unroll
        for (int kj = 0; kj < 7; ++kj) {
            int nb = (pi + ki) * 10 + (pj + kj);
            half8 vv = *reinterpret_cast<const half8*>(&vsm[nb * KVS + h * 32 + sub * 8]);
            float wgt = logits[ki * 7 + kj];
#pragma unroll
            for (int i = 0; i < 8; ++i)
                o[i] += wgt * (float)vv[i];
        }
    }

    // ---- proj W B-fragments -> registers (issued now; consumed after bar3,
    //      latency hidden under att-write + barrier sync) ----
    const int l   = t & 63;
    const int wv  = t >> 6;           // 0..7
    const int wm  = wv & 1;           // M tile (16 px)
    const int wn  = wv >> 1;          // N tile (32 cols)
    const int kb0 = (l >> 4) << 3;
    half8 wreg[8];
#pragma unroll
    for (int ks = 0; ks < 4; ++ks) {
        const _Float16* wp = pwh + (size_t)(wn * 32 + (l & 15)) * 128 + ks * 32 + kb0;
        wreg[ks]     = *reinterpret_cast<const half8*>(wp);
        wreg[4 + ks] = *reinterpret_cast<const half8*>(wp + 16 * 128);
    }

    // ---- att -> LDS (K region), fp16 ----
    {
        half8 r;
#pragma unroll
        for (int i = 0; i < 8; ++i) r[i] = (_Float16)(o[i] * inv);
        *reinterpret_cast<half8*>(&atts[px * KVS + h * 32 + sub * 8]) = r;
    }

    __syncthreads();                                   // bar3: att ready

    // ---- projection: out[32px][128] = att @ Wp^T + pb (B from registers) ----
    f32x4 acc0 = (f32x4){0.f, 0.f, 0.f, 0.f};
    f32x4 acc1 = (f32x4){0.f, 0.f, 0.f, 0.f};
#pragma unroll
    for (int ks = 0; ks < 4; ++ks) {
        const int kb = ks * 32 + kb0;
        half8 a = *reinterpret_cast<const half8*>(&atts[(wm * 16 + (l & 15)) * KVS + kb]);
        acc0 = __builtin_amdgcn_mfma_f32_16x16x32_f16(a, wreg[ks],     acc0, 0, 0, 0);
        acc1 = __builtin_amdgcn_mfma_f32_16x16x32_f16(a, wreg[4 + ks], acc1, 0, 0, 0);
    }

#pragma unroll
    for (int r = 0; r < 4; ++r) {
        int prow = wm * 16 + ((l >> 4) << 2) + r;          // local pixel 0..31
        int gpix = (ti + (prow >> 2)) * 56 + tj + (prow & 3);
        float* dst = out + ((size_t)b * NPIX + gpix) * 128;
        int c0 = wn * 32 + (l & 15);
        dst[c0]      = acc0[r] + pb[c0];
        dst[c0 + 16] = acc1[r] + pb[c0 + 16];
    }
}

// ---------------------------------------------------------------------------
extern "C" void kernel_launch(void* const* d_in, const int* in_sizes, int n_in,
                              void* d_out, int out_size, void* d_ws, size_t ws_size,
                              hipStream_t stream)
{
    const float* x      = (const float*)d_in[0];
    const float* qkv_w  = (const float*)d_in[1];
    const float* qkv_b  = (const float*)d_in[2];
    const float* rpb    = (const float*)d_in[3];
    const float* proj_w = (const float*)d_in[4];
    const float* proj_b = (const float*)d_in[5];
    float* out = (float*)d_out;

    // ws layout (fp16): q | k | v (3.2 MB each, [b][pix][128]) | proj_w fp16
    _Float16* qbuf = (_Float16*)d_ws;
    _Float16* kbuf = qbuf + (size_t)QKV_STRIDE;
    _Float16* vbuf = kbuf + (size_t)QKV_STRIDE;
    _Float16* pwh  = vbuf + (size_t)QKV_STRIDE;   // 128*128 halves = 32 KB

    // opt-in to 76,160B dynamic LDS (>64KB default cap); host-side, graph-safe
    hipFuncSetAttribute((const void*)natten_proj_k,
                        hipFuncAttributeMaxDynamicSharedMemorySize,
                        2 * HP * KVS * (int)sizeof(_Float16));

    // 1) QKV projection (+ folded proj_w fp16 conversion), K-pipelined staging
    qkv_mfma<64, 128, 2, 2><<<dim3(196, 3), dim3(256), 0, stream>>>(
        x, qkv_w, qkv_b, qbuf, proj_w, pwh);

    // 2) fused neighborhood attention + output projection, XCD-swizzled grid
    natten_proj_k<<<dim3(392), dim3(512),
                    2 * HP * KVS * sizeof(_Float16), stream>>>(
        qbuf, kbuf, vbuf, rpb, pwh, proj_b, out);
}